// Round 7
// baseline (319.887 us; speedup 1.0000x reference)
//
#include <hip/hip_runtime.h>
#include <hip/hip_bf16.h>

using bf16_t = __bf16;
using bf16x8 = __attribute__((ext_vector_type(8))) __bf16;
using bf16x4 = __attribute__((ext_vector_type(4))) __bf16;
using f32x4  = __attribute__((ext_vector_type(4))) float;

#define S_  2048
#define D_  1024

typedef __attribute__((address_space(1))) unsigned int glb_u32;
typedef __attribute__((address_space(3))) unsigned int lds_u32;

__device__ __forceinline__ void async_cp16(const void* g, void* lds) {
    __builtin_amdgcn_global_load_lds(
        (glb_u32*)(unsigned long long)g,
        (lds_u32*)(unsigned int)(unsigned long long)lds,
        16, 0, 0);
}

// ---------------- weights f32 -> bf16 ----------------
__global__ __launch_bounds__(256) void cast4_f32_bf16(const float* __restrict__ a, const float* __restrict__ b,
                                                      const float* __restrict__ c, const float* __restrict__ dd,
                                                      bf16_t* __restrict__ oa, bf16_t* __restrict__ ob,
                                                      bf16_t* __restrict__ oc, bf16_t* __restrict__ od, int n4) {
    int i = blockIdx.x * 256 + threadIdx.x;
    if (i >= n4) return;
    const float* s; bf16_t* d;
    int w = blockIdx.y;
    if      (w == 0) { s = a;  d = oa; }
    else if (w == 1) { s = b;  d = ob; }
    else if (w == 2) { s = c;  d = oc; }
    else             { s = dd; d = od; }
    float4 f = reinterpret_cast<const float4*>(s)[i];
    bf16x4 o;
    o[0] = (bf16_t)f.x; o[1] = (bf16_t)f.y; o[2] = (bf16_t)f.z; o[3] = (bf16_t)f.w;
    reinterpret_cast<bf16x4*>(d)[i] = o;
}

// ---------------- activations f32 -> bf16 (q,k,v) ----------------
__global__ __launch_bounds__(256) void cast3_f32_bf16(const float* __restrict__ q, const float* __restrict__ k,
                                                      const float* __restrict__ v,
                                                      bf16_t* __restrict__ oq, bf16_t* __restrict__ ok,
                                                      bf16_t* __restrict__ ov, int n4) {
    int i = blockIdx.x * 256 + threadIdx.x;
    if (i >= n4) return;
    const float* s; bf16_t* d;
    int w = blockIdx.y;
    if      (w == 0) { s = q; d = oq; }
    else if (w == 1) { s = k; d = ok; }
    else             { s = v; d = ov; }
    float4 f = reinterpret_cast<const float4*>(s)[i];
    bf16x4 o;
    o[0] = (bf16_t)f.x; o[1] = (bf16_t)f.y; o[2] = (bf16_t)f.z; o[3] = (bf16_t)f.w;
    reinterpret_cast<bf16x4*>(d)[i] = o;
}

// ================= 8-phase 256x256 GEMM (m201 template port) =================
// C[M x 1024] = A[M x 1024] * W[1024 x 1024]^T, A/W bf16.
// BK=64, 16 K-tiles; 512 threads = 8 waves (2M x 4N), per-wave out 128x64.
// LDS 128KB: As/Bs [2 dbuf][2 khalf][256 rows x 32 k], pure global_load_lds
// staging (source-swizzled slot^((row>>1)&3), LDS DMA-linear).
// Phases per K-tile: (kh0,mlo)(kh0,mhi)(kh1,mlo)(kh1,mhi); per phase:
//   ds_read 8 (even) / 4 (odd) b128 -> stage 1 half-tile (2 cp16) ->
//   s_barrier -> lgkmcnt(0) -> sched_barrier(0) -> setprio(1) -> 16 MFMA ->
//   setprio(0) -> [odd phases: s_waitcnt vmcnt(4), last tile: vmcnt(0)] -> s_barrier
// Stage-ahead = 4 half-tiles (one K-tile). Guard proof: at end of odd phase,
// outstanding = 8 loads (4 half-tiles); vmcnt(4) completes the oldest 2 halves,
// exactly the ones the next even phase reads. Never drains to 0 mid-loop.
// MODE 0: fused QKV (z from blockIdx; z0 scale=cs; z2 writes per-head V^T with
//         s pre-permuted to MFMA A-frag order). grid 384 x 512.
// MODE 1: out-projection, C f32. grid 128 x 512.
template <int MODE>
__global__ __launch_bounds__(512, 2) void gemm8(const bf16_t* __restrict__ Aq,
                                                const bf16_t* __restrict__ Ak,
                                                const bf16_t* __restrict__ Av,
                                                const bf16_t* __restrict__ Wq,
                                                const bf16_t* __restrict__ Wk,
                                                const bf16_t* __restrict__ Wv,
                                                bf16_t* __restrict__ Qp,
                                                bf16_t* __restrict__ Kp,
                                                bf16_t* __restrict__ Vt,
                                                float cs,
                                                float* __restrict__ Co) {
    __shared__ bf16_t As[2][2][256 * 32];   // [buf][khalf][row*32 + k]
    __shared__ bf16_t Bs[2][2][256 * 32];
    const int K = 1024;
    constexpr int NKT = 16;                 // K / 64
    int tid  = threadIdx.x;
    int lane = tid & 63, w = tid >> 6;
    int l15  = lane & 15, quad = lane >> 4;
    int wr = w >> 2, wc = w & 3;            // 2M x 4N wave grid

    int bid = blockIdx.x;
    int xcd = bid & 7, r = bid >> 3;
    int z = 0, r2 = r;
    if (MODE == 0) { z = r >> 4; r2 = r & 15; }
    int m0 = (xcd * 4 + (r2 & 3)) * 256;
    int n0 = (r2 >> 2) * 256;

    const bf16_t *Ag, *Bg;
    if (MODE == 0) {
        Ag = (z == 0) ? Aq : (z == 1) ? Ak : Av;
        Bg = (z == 0) ? Wq : (z == 1) ? Wk : Wv;
    } else { Ag = Aq; Bg = Wq; }

    // staging: half-tile = 256 rows x 32 k x bf16 = 16KB = 2 cp16/thread
    const bf16_t* aS[2]; const bf16_t* bS[2]; int ldOff[2];
#pragma unroll
    for (int j = 0; j < 2; j++) {
        int c = j * 512 + tid;
        int row = c >> 2, s = c & 3;
        int ks = (s ^ ((row >> 1) & 3)) * 8;          // source swizzle
        aS[j] = Ag + (size_t)(m0 + row) * K + ks;
        bS[j] = Bg + (size_t)(n0 + row) * K + ks;
        ldOff[j] = c * 8;
    }
    auto stage = [&](int buf, int t, int half) {       // half: 0=Akh0 1=Bkh0 2=Akh1 3=Bkh1
        int kh = half >> 1;
        int koff = t * 64 + kh * 32;
        if ((half & 1) == 0) {
            async_cp16(aS[0] + koff, &As[buf][kh][ldOff[0]]);
            async_cp16(aS[1] + koff, &As[buf][kh][ldOff[1]]);
        } else {
            async_cp16(bS[0] + koff, &Bs[buf][kh][ldOff[0]]);
            async_cp16(bS[1] + koff, &Bs[buf][kh][ldOff[1]]);
        }
    };

    // fragment read offsets (swizzled, conflict-free 2-way)
    int aoff[8], boff[4];
#pragma unroll
    for (int i = 0; i < 8; i++) {
        int row = wr * 128 + i * 16 + l15;
        aoff[i] = row * 32 + ((quad ^ ((row >> 1) & 3)) * 8);
    }
#pragma unroll
    for (int jn = 0; jn < 4; jn++) {
        int row = wc * 64 + jn * 16 + l15;
        boff[jn] = row * 32 + ((quad ^ ((row >> 1) & 3)) * 8);
    }

    f32x4 acc[8][4] = {};

    // prologue: all 4 halves of tile 0; complete the kh0 halves, keep kh1 in flight
    stage(0, 0, 0); stage(0, 0, 1); stage(0, 0, 2); stage(0, 0, 3);
    asm volatile("s_waitcnt vmcnt(4)" ::: "memory");
    __builtin_amdgcn_s_barrier();

    for (int t = 0; t < NKT; ++t) {
        int buf = t & 1, nbuf = buf ^ 1;
        bool st = (t + 1 < NKT);
        const bf16_t* A0 = As[buf][0]; const bf16_t* A1 = As[buf][1];
        const bf16_t* B0 = Bs[buf][0]; const bf16_t* B1 = Bs[buf][1];
        bf16x8 af[4], bfr[4];

        // ---- phase 0: kh0, m 0..3 ----
#pragma unroll
        for (int i = 0; i < 4; i++) af[i] = *reinterpret_cast<const bf16x8*>(&A0[aoff[i]]);
#pragma unroll
        for (int jn = 0; jn < 4; jn++) bfr[jn] = *reinterpret_cast<const bf16x8*>(&B0[boff[jn]]);
        if (st) stage(nbuf, t + 1, 0);
        __builtin_amdgcn_s_barrier();
        asm volatile("s_waitcnt lgkmcnt(0)" ::: "memory");
        __builtin_amdgcn_sched_barrier(0);
        __builtin_amdgcn_s_setprio(1);
#pragma unroll
        for (int i = 0; i < 4; i++)
#pragma unroll
            for (int jn = 0; jn < 4; jn++)
                acc[i][jn] = __builtin_amdgcn_mfma_f32_16x16x32_bf16(af[i], bfr[jn], acc[i][jn], 0, 0, 0);
        __builtin_amdgcn_s_setprio(0);
        __builtin_amdgcn_s_barrier();

        // ---- phase 1: kh0, m 4..7 (reuse bfr) ----
#pragma unroll
        for (int i = 0; i < 4; i++) af[i] = *reinterpret_cast<const bf16x8*>(&A0[aoff[4 + i]]);
        if (st) stage(nbuf, t + 1, 1);
        __builtin_amdgcn_s_barrier();
        asm volatile("s_waitcnt lgkmcnt(0)" ::: "memory");
        __builtin_amdgcn_sched_barrier(0);
        __builtin_amdgcn_s_setprio(1);
#pragma unroll
        for (int i = 0; i < 4; i++)
#pragma unroll
            for (int jn = 0; jn < 4; jn++)
                acc[4 + i][jn] = __builtin_amdgcn_mfma_f32_16x16x32_bf16(af[i], bfr[jn], acc[4 + i][jn], 0, 0, 0);
        __builtin_amdgcn_s_setprio(0);
        if (t == NKT - 1) asm volatile("s_waitcnt vmcnt(0)" ::: "memory");
        else              asm volatile("s_waitcnt vmcnt(4)" ::: "memory");
        __builtin_amdgcn_s_barrier();

        // ---- phase 2: kh1, m 0..3 ----
#pragma unroll
        for (int i = 0; i < 4; i++) af[i] = *reinterpret_cast<const bf16x8*>(&A1[aoff[i]]);
#pragma unroll
        for (int jn = 0; jn < 4; jn++) bfr[jn] = *reinterpret_cast<const bf16x8*>(&B1[boff[jn]]);
        if (st) stage(nbuf, t + 1, 2);
        __builtin_amdgcn_s_barrier();
        asm volatile("s_waitcnt lgkmcnt(0)" ::: "memory");
        __builtin_amdgcn_sched_barrier(0);
        __builtin_amdgcn_s_setprio(1);
#pragma unroll
        for (int i = 0; i < 4; i++)
#pragma unroll
            for (int jn = 0; jn < 4; jn++)
                acc[i][jn] = __builtin_amdgcn_mfma_f32_16x16x32_bf16(af[i], bfr[jn], acc[i][jn], 0, 0, 0);
        __builtin_amdgcn_s_setprio(0);
        __builtin_amdgcn_s_barrier();

        // ---- phase 3: kh1, m 4..7 ----
#pragma unroll
        for (int i = 0; i < 4; i++) af[i] = *reinterpret_cast<const bf16x8*>(&A1[aoff[4 + i]]);
        if (st) stage(nbuf, t + 1, 3);
        __builtin_amdgcn_s_barrier();
        asm volatile("s_waitcnt lgkmcnt(0)" ::: "memory");
        __builtin_amdgcn_sched_barrier(0);
        __builtin_amdgcn_s_setprio(1);
#pragma unroll
        for (int i = 0; i < 4; i++)
#pragma unroll
            for (int jn = 0; jn < 4; jn++)
                acc[4 + i][jn] = __builtin_amdgcn_mfma_f32_16x16x32_bf16(af[i], bfr[jn], acc[4 + i][jn], 0, 0, 0);
        __builtin_amdgcn_s_setprio(0);
        asm volatile("s_waitcnt vmcnt(4)" ::: "memory");   // guard next tile's phase-0 halves
        __builtin_amdgcn_s_barrier();
    }

    // ---- epilogue ----
    if (MODE == 0 && z == 2) {
#pragma unroll
        for (int i = 0; i < 8; i++)
#pragma unroll
            for (int jn = 0; jn < 4; jn++) {
                int m = m0 + wr * 128 + i * 16 + quad * 4;   // s-dim base (4 consecutive)
                int n = n0 + wc * 64 + jn * 16 + l15;        // d-dim
                bf16x4 o4;
#pragma unroll
                for (int rr = 0; rr < 4; rr++) o4[rr] = (bf16_t)acc[i][jn][rr];
                size_t vrow = (size_t)((m >> 11) * 16 + (n >> 6)) * 64 + (n & 63);
                int ml = m & 2047;
                int mp = (ml & ~31) | (((ml >> 2) & 3) << 3) | (((ml >> 4) & 1) << 2);
                *reinterpret_cast<bf16x4*>(&Vt[vrow * S_ + mp]) = o4;
            }
    } else if (MODE == 0) {
        bf16_t* CoH = (z == 0) ? Qp : Kp;
        float scale = (z == 0) ? cs : 1.0f;
#pragma unroll
        for (int i = 0; i < 8; i++)
#pragma unroll
            for (int jn = 0; jn < 4; jn++)
#pragma unroll
                for (int rr = 0; rr < 4; rr++) {
                    int m = m0 + wr * 128 + i * 16 + quad * 4 + rr;
                    int n = n0 + wc * 64 + jn * 16 + l15;
                    CoH[(size_t)m * 1024 + n] = (bf16_t)(acc[i][jn][rr] * scale);
                }
    } else {
#pragma unroll
        for (int i = 0; i < 8; i++)
#pragma unroll
            for (int jn = 0; jn < 4; jn++)
#pragma unroll
                for (int rr = 0; rr < 4; rr++) {
                    int m = m0 + wr * 128 + i * 16 + quad * 4 + rr;
                    int n = n0 + wc * 64 + jn * 16 + l15;
                    Co[(size_t)m * 1024 + n] = acc[i][jn][rr];
                }
    }
}

// ============== fallback path kernels (R6, used if ws too small) ==============
__global__ __launch_bounds__(256, 4) void qkv_gemm(const float* __restrict__ qf,
                                                   const float* __restrict__ kf,
                                                   const float* __restrict__ vf,
                                                   const bf16_t* __restrict__ Wqb,
                                                   const bf16_t* __restrict__ Wkb,
                                                   const bf16_t* __restrict__ Wvb,
                                                   bf16_t* __restrict__ Qp,
                                                   bf16_t* __restrict__ Kp,
                                                   bf16_t* __restrict__ Vt,
                                                   float cs) {
    __shared__ bf16_t As[2][128 * 32];
    __shared__ bf16_t Bs[3][128 * 32];
    const int K = 1024;
    int tid  = threadIdx.x;
    int lane = tid & 63;
    int w    = tid >> 6;
    int l15  = lane & 15, quad = lane >> 4;

    int bid = blockIdx.x;
    int xcd = bid & 7, idx = bid >> 3;
    int z   = idx >> 6;
    int rem = idx & 63;
    int m0 = (xcd * 8 + (rem & 7)) * 128;
    int n0 = (rem >> 3) * 128;
    int wm = (w >> 1) * 64, wn = (w & 1) * 64;

    const float*  Af; const bf16_t* Bt;
    if      (z == 0) { Af = qf; Bt = Wqb; }
    else if (z == 1) { Af = kf; Bt = Wkb; }
    else             { Af = vf; Bt = Wvb; }
    float scale = (z == 0) ? cs : 1.0f;

    const float* Ag = Af + (size_t)(m0 + (tid >> 2)) * K + (tid & 3) * 8;
    int arow = tid >> 2, aslot = tid & 3;
    int aoff = arow * 32 + ((aslot ^ ((arow >> 1) & 3)) * 8);

    const bf16_t* bSrc[2]; int bOff[2];
#pragma unroll
    for (int j = 0; j < 2; j++) {
        int linear = j * 256 + tid;
        int row = linear >> 2, s = linear & 3;
        bSrc[j] = Bt + (size_t)(n0 + row) * K + ((s ^ ((row >> 1) & 3)) * 8);
        bOff[j] = linear * 8;
    }

    float4 aE[4], aO[4];
    auto loadA = [&](float4* a, int k0) {
        const float* p = Ag + k0;
        a[0] = *reinterpret_cast<const float4*>(p);
        a[1] = *reinterpret_cast<const float4*>(p + 4);
        a[2] = *reinterpret_cast<const float4*>(p + (size_t)64 * K);
        a[3] = *reinterpret_cast<const float4*>(p + (size_t)64 * K + 4);
    };
    auto storeA = [&](bf16_t* dst, const float4* a) {
        bf16x8 o0, o1;
        o0[0] = (bf16_t)a[0].x; o0[1] = (bf16_t)a[0].y; o0[2] = (bf16_t)a[0].z; o0[3] = (bf16_t)a[0].w;
        o0[4] = (bf16_t)a[1].x; o0[5] = (bf16_t)a[1].y; o0[6] = (bf16_t)a[1].z; o0[7] = (bf16_t)a[1].w;
        o1[0] = (bf16_t)a[2].x; o1[1] = (bf16_t)a[2].y; o1[2] = (bf16_t)a[2].z; o1[3] = (bf16_t)a[2].w;
        o1[4] = (bf16_t)a[3].x; o1[5] = (bf16_t)a[3].y; o1[6] = (bf16_t)a[3].z; o1[7] = (bf16_t)a[3].w;
        *reinterpret_cast<bf16x8*>(dst + aoff)        = o0;
        *reinterpret_cast<bf16x8*>(dst + aoff + 2048) = o1;
    };
    auto stageB = [&](bf16_t* dst, int k0) {
        async_cp16(bSrc[0] + k0, dst + bOff[0]);
        async_cp16(bSrc[1] + k0, dst + bOff[1]);
    };

    f32x4 acc[4][4] = {};
    bf16_t *bRead = Bs[0], *bMid = Bs[1], *bStage = Bs[2];

    loadA(aE, 0);
    stageB(Bs[0], 0);
    loadA(aO, 32);
    stageB(Bs[1], 32);
    storeA(As[0], aE);
    asm volatile("s_waitcnt vmcnt(6) lgkmcnt(0)" ::: "memory");
    __builtin_amdgcn_s_barrier();

#pragma unroll 2
    for (int i = 0; i < 32; ++i) {
        int k2 = (i + 2 < 32) ? (i + 2) * 32 : 992;
        float4* aNew = (i & 1) ? aO : aE;
        loadA(aNew, k2);
        stageB(bStage, k2);

        const bf16_t* Ac = As[i & 1];
        bf16x8 af[4], bfr[4];
#pragma unroll
        for (int t = 0; t < 4; t++) {
            int ra = wm + t * 16 + l15;
            int rb = wn + t * 16 + l15;
            af[t]  = *reinterpret_cast<const bf16x8*>(&Ac[ra * 32 + ((quad ^ ((ra >> 1) & 3)) * 8)]);
            bfr[t] = *reinterpret_cast<const bf16x8*>(&bRead[rb * 32 + ((quad ^ ((rb >> 1) & 3)) * 8)]);
        }
#pragma unroll
        for (int mt = 0; mt < 4; mt++)
#pragma unroll
            for (int nt = 0; nt < 4; nt++)
                acc[mt][nt] = __builtin_amdgcn_mfma_f32_16x16x32_bf16(af[mt], bfr[nt], acc[mt][nt], 0, 0, 0);

        if (i + 1 < 32) storeA(As[(i + 1) & 1], (i & 1) ? aE : aO);

        bf16_t* t0 = bRead; bRead = bMid; bMid = bStage; bStage = t0;
        asm volatile("s_waitcnt vmcnt(6) lgkmcnt(0)" ::: "memory");
        __builtin_amdgcn_s_barrier();
    }

    if (z == 2) {
#pragma unroll
        for (int mt = 0; mt < 4; mt++)
#pragma unroll
            for (int nt = 0; nt < 4; nt++) {
                int m = m0 + wm + mt * 16 + quad * 4;
                int n = n0 + wn + nt * 16 + l15;
                bf16x4 o4;
#pragma unroll
                for (int r = 0; r < 4; r++) o4[r] = (bf16_t)acc[mt][nt][r];
                size_t vrow = (size_t)((m >> 11) * 16 + (n >> 6)) * 64 + (n & 63);
                int ml = m & 2047;
                int mp = (ml & ~31) | (((ml >> 2) & 3) << 3) | (((ml >> 4) & 1) << 2);
                *reinterpret_cast<bf16x4*>(&Vt[vrow * S_ + mp]) = o4;
            }
    } else {
        bf16_t* Co = (z == 0) ? Qp : Kp;
#pragma unroll
        for (int mt = 0; mt < 4; mt++)
#pragma unroll
            for (int nt = 0; nt < 4; nt++)
#pragma unroll
                for (int r = 0; r < 4; r++) {
                    int m = m0 + wm + mt * 16 + quad * 4 + r;
                    int n = n0 + wn + nt * 16 + l15;
                    Co[(size_t)m * 1024 + n] = (bf16_t)(acc[mt][nt][r] * scale);
                }
    }
}

// ---------------- fused masked attention (measured-best 81us version) ----------------
__global__ __launch_bounds__(256) void attn_fused(const bf16_t* __restrict__ Qp,
                                                  const bf16_t* __restrict__ Kp,
                                                  const bf16_t* __restrict__ Vt,
                                                  const int* __restrict__ vlen_p,
                                                  bf16_t* __restrict__ Out) {
    __shared__ bf16_t smem[4][64 * 64];

    int tid  = threadIdx.x;
    int lane = tid & 63, w = tid >> 6;
    int l15  = lane & 15, quad = lane >> 4;

    int nk[4], ord[4] = {0, 1, 2, 3};
#pragma unroll
    for (int i = 0; i < 4; i++) nk[i] = (vlen_p[i] + 63) >> 6;
#pragma unroll
    for (int i = 0; i < 3; i++)
#pragma unroll
        for (int j = 0; j < 3 - i; j++)
            if (nk[ord[j + 1]] > nk[ord[j]]) { int t = ord[j]; ord[j] = ord[j + 1]; ord[j + 1] = t; }

    int bid  = blockIdx.x;
    int b    = ord[bid >> 9];
    int t    = bid & 511;
    int h    = (t & 7) * 2 + ((t >> 3) & 1);
    int qblk = t >> 4;
    int vlen = vlen_p[b];
    int nkb  = (vlen + 63) >> 6;

    const bf16_t* Qg = Qp + (size_t)(b * S_ + qblk * 64) * D_ + h * 64;
    const bf16_t* Kg = Kp + (size_t)b * S_ * D_ + h * 64;
    const bf16_t* Vg = Vt + (size_t)(b * 16 + h) * 64 * S_;

    int r0 = tid >> 3, s0 = tid & 7;
    int sx = (s0 ^ (r0 & 7)) * 8;
    const bf16_t* kS0 = Kg + (size_t)r0 * D_ + sx;
    const bf16_t* kS1 = kS0 + (size_t)32 * D_;
    const bf16_t* vS0 = Vg + (size_t)r0 * S_ + sx;
    const bf16_t* vS1 = vS0 + (size_t)32 * S_;

    {
        const bf16_t* qS0 = Qg + (size_t)r0 * D_ + sx;
        async_cp16(qS0,                   smem[2] + tid * 8);
        async_cp16(qS0 + (size_t)32 * D_, smem[2] + tid * 8 + 2048);
        async_cp16(kS0, smem[0] + tid * 8);
        async_cp16(kS1, smem[0] + tid * 8 + 2048);
        async_cp16(vS0, smem[1] + tid * 8);
        async_cp16(vS1, smem[1] + tid * 8 + 2048);
    }
    __syncthreads();

    bf16x8 qf[2];
    {
        int row = w * 16 + l15, x = row & 7;
#pragma unroll
        for (int kk = 0; kk < 2; kk++)
            qf[kk] = *reinterpret_cast<const bf16x8*>(&smem[2][row * 64 + ((kk * 4 + quad) ^ x) * 8]);
    }
    __syncthreads();

    f32x4 o[4] = {};
    float l_st = 0.f;

    for (int kb = 0; kb < nkb; kb++) {
        int cur = kb & 1;
        if (kb + 1 < nkb) {
            int nxt = cur ^ 1;
            kS0 += (size_t)64 * D_; kS1 += (size_t)64 * D_;
            vS0 += 64;              vS1 += 64;
            async_cp16(kS0, smem[nxt * 2]     + tid * 8);
            async_cp16(kS1, smem[nxt * 2]     + tid * 8 + 2048);
            async_cp16(vS0, smem[nxt * 2 + 1] + tid * 8);
            async_cp16(vS1, smem[nxt * 2 + 1] + tid * 8 + 2048);
        }
        const bf16_t* Kc = smem[cur * 2];
        const bf16_t* Vc = smem[cur * 2 + 1];

        f32x4 sc[4] = {};
#pragma unroll
        for (int nt = 0; nt < 4; nt++) {
            int row = nt * 16 + l15, x = row & 7;
#pragma unroll
            for (int kk = 0; kk < 2; kk++) {
                bf16x8 kf = *reinterpret_cast<const bf16x8*>(&Kc[row * 64 + ((kk * 4 + quad) ^ x) * 8]);
                sc[nt] = __builtin_amdgcn_mfma_f32_16x16x32_bf16(kf, qf[kk], sc[nt], 0, 0, 0);
            }
        }

        bool partial = (vlen & 63) && (kb == nkb - 1);
        bf16x8 pf[2];
        float lacc = 0.f;
        if (!partial) {
#pragma unroll
            for (int nt = 0; nt < 4; nt++)
#pragma unroll
                for (int r = 0; r < 4; r++) {
                    float p = __builtin_exp2f(sc[nt][r]);
                    lacc += p;
                    pf[nt >> 1][(nt & 1) * 4 + r] = (bf16_t)p;
                }
        } else {
#pragma unroll
            for (int nt = 0; nt < 4; nt++)
#pragma unroll
                for (int r = 0; r < 4; r++) {
                    float p = __builtin_exp2f(sc[nt][r]);
                    if (kb * 64 + nt * 16 + quad * 4 + r >= vlen) p = 0.f;
                    lacc += p;
                    pf[nt >> 1][(nt & 1) * 4 + r] = (bf16_t)p;
                }
        }
        l_st += lacc;

#pragma unroll
        for (int np = 0; np < 2; np++)
#pragma unroll
            for (int dt = 0; dt < 4; dt++) {
                int row = dt * 16 + l15, x = row & 7;
                bf16x8 vfr = *reinterpret_cast<const bf16x8*>(&Vc[row * 64 + ((np * 4 + quad) ^ x) * 8]);
                o[dt] = __builtin_amdgcn_mfma_f32_16x16x32_bf16(vfr, pf[np], o[dt], 0, 0, 0);
            }

        __syncthreads();
    }

    float l = l_st;
    l += __shfl_xor(l, 16);
    l += __shfl_xor(l, 32);
    float inv = 1.0f / l;

    bf16_t* T = smem[0];
    {
        int row = w * 16 + l15, x = row & 7;
#pragma unroll
        for (int dt = 0; dt < 4; dt++) {
            bf16x4 o4;
#pragma unroll
            for (int r = 0; r < 4; r++) o4[r] = (bf16_t)(o[dt][r] * inv);
            int slot = dt * 2 + (quad >> 1);
            *reinterpret_cast<bf16x4*>(&T[row * 64 + (slot ^ x) * 8 + (quad & 1) * 4]) = o4;
        }
    }
    __syncthreads();
    {
        int row = tid >> 2, ch = tid & 3, x = row & 7;
        size_t obase = (size_t)(b * S_ + qblk * 64 + row) * D_ + h * 64 + ch * 16;
        bf16x8 f0 = *reinterpret_cast<const bf16x8*>(&T[row * 64 + ((ch * 2)     ^ x) * 8]);
        bf16x8 f1 = *reinterpret_cast<const bf16x8*>(&T[row * 64 + ((ch * 2 + 1) ^ x) * 8]);
        *reinterpret_cast<bf16x8*>(&Out[obase])     = f0;
        *reinterpret_cast<bf16x8*>(&Out[obase + 8]) = f1;
    }
}

// ---------------- fallback output GEMM (R6 ring) ----------------
__global__ __launch_bounds__(256) void gemm_out(const bf16_t* __restrict__ A,
                                                const bf16_t* __restrict__ Bt,
                                                float* __restrict__ C) {
    __shared__ bf16_t As[3][128 * 32];
    __shared__ bf16_t Bs[3][128 * 32];
    const int K = 1024;
    int tid  = threadIdx.x;
    int lane = tid & 63;
    int w    = tid >> 6;
    int l15  = lane & 15, quad = lane >> 4;

    int bid = blockIdx.x;
    int xcd = bid & 7, idx = bid >> 3;
    int m0 = (xcd * 8 + (idx & 7)) * 128;
    int n0 = (idx >> 3) * 128;
    int wm = (w >> 1) * 64, wn = (w & 1) * 64;

    const bf16_t* aSrc[2]; const bf16_t* bSrc[2];
    int dOff[2];
#pragma unroll
    for (int j = 0; j < 2; j++) {
        int linear = j * 256 + tid;
        int row = linear >> 2, s = linear & 3;
        int sw = (s ^ ((row >> 1) & 3)) * 8;
        aSrc[j] = A  + (size_t)(m0 + row) * K + sw;
        bSrc[j] = Bt + (size_t)(n0 + row) * K + sw;
        dOff[j] = linear * 8;
    }

    auto stage = [&](int buf, int koff) {
#pragma unroll
        for (int j = 0; j < 2; j++) async_cp16(aSrc[j] + koff, &As[buf][dOff[j]]);
#pragma unroll
        for (int j = 0; j < 2; j++) async_cp16(bSrc[j] + koff, &Bs[buf][dOff[j]]);
    };

    f32x4 acc[4][4] = {};

    stage(0, 0);
    stage(1, 32);

    int cur = 0, nx2 = 2;
    for (int i = 0; i < 32; ++i) {
        if (i == 31) asm volatile("s_waitcnt vmcnt(0)" ::: "memory");
        else         asm volatile("s_waitcnt vmcnt(4)" ::: "memory");
        __builtin_amdgcn_s_barrier();
        if (i + 2 < 32) stage(nx2, (i + 2) * 32);

        bf16x8 af[4], bfr[4];
#pragma unroll
        for (int t = 0; t < 4; t++) {
            int ra = wm + t * 16 + l15;
            int rb = wn + t * 16 + l15;
            af[t]  = *reinterpret_cast<const bf16x8*>(&As[cur][ra * 32 + ((quad ^ ((ra >> 1) & 3)) * 8)]);
            bfr[t] = *reinterpret_cast<const bf16x8*>(&Bs[cur][rb * 32 + ((quad ^ ((rb >> 1) & 3)) * 8)]);
        }
#pragma unroll
        for (int mt = 0; mt < 4; mt++)
#pragma unroll
            for (int nt = 0; nt < 4; nt++)
                acc[mt][nt] = __builtin_amdgcn_mfma_f32_16x16x32_bf16(af[mt], bfr[nt], acc[mt][nt], 0, 0, 0);

        cur = (cur == 2) ? 0 : cur + 1;
        nx2 = (nx2 == 2) ? 0 : nx2 + 1;
    }

#pragma unroll
    for (int mt = 0; mt < 4; mt++)
#pragma unroll
        for (int nt = 0; nt < 4; nt++)
#pragma unroll
            for (int r = 0; r < 4; r++) {
                int m = m0 + wm + mt * 16 + quad * 4 + r;
                int n = n0 + wn + nt * 16 + l15;
                C[(size_t)m * 1024 + n] = acc[mt][nt][r];
            }
}

extern "C" void kernel_launch(void* const* d_in, const int* in_sizes, int n_in,
                              void* d_out, int out_size, void* d_ws, size_t ws_size,
                              hipStream_t stream) {
    const float* q  = (const float*)d_in[0];
    const float* k  = (const float*)d_in[1];
    const float* v  = (const float*)d_in[2];
    const int*   vl = (const int*)d_in[3];
    const float* Wq = (const float*)d_in[4];
    const float* Wk = (const float*)d_in[5];
    const float* Wv = (const float*)d_in[6];
    const float* Wo = (const float*)d_in[7];
    float* out = (float*)d_out;

    bf16_t* ws = (bf16_t*)d_ws;
    const size_t SD = (size_t)8192 * 1024;
    const size_t WW = (size_t)1024 * 1024;
    const float cs = 0.18033688f;  // (1/8)*log2(e) baked into Q projection
    dim3 blk(256);

    size_t need = (6 * SD + 4 * WW) * sizeof(bf16_t);   // ~109 MB
    if (ws_size >= need) {
        // ---- 8-phase path: pre-cast activations, m201-template GEMMs ----
        bf16_t* qb  = ws;              // q bf16; reused as attn output after qkv
        bf16_t* kb  = ws + SD;
        bf16_t* vb  = ws + 2 * SD;
        bf16_t* Qp  = ws + 3 * SD;
        bf16_t* Kp  = ws + 4 * SD;
        bf16_t* Vt  = ws + 5 * SD;
        bf16_t* Wqb = ws + 6 * SD;
        bf16_t* Wkb = Wqb + WW;
        bf16_t* Wvb = Wqb + 2 * WW;
        bf16_t* Wob = Wqb + 3 * WW;

        cast4_f32_bf16<<<dim3(1024, 4), blk, 0, stream>>>(Wq, Wk, Wv, Wo, Wqb, Wkb, Wvb, Wob, 262144);
        cast3_f32_bf16<<<dim3(8192, 3), blk, 0, stream>>>(q, k, v, qb, kb, vb, 2097152);
        gemm8<0><<<dim3(384), dim3(512), 0, stream>>>(qb, kb, vb, Wqb, Wkb, Wvb, Qp, Kp, Vt, cs, nullptr);
        attn_fused<<<dim3(2048), blk, 0, stream>>>(Qp, Kp, Vt, vl, qb);
        gemm8<1><<<dim3(128), dim3(512), 0, stream>>>(qb, nullptr, nullptr, Wob, nullptr, nullptr,
                                                      nullptr, nullptr, nullptr, 1.0f, out);
    } else {
        // ---- fallback: R6 path (92.3 MB footprint, known-good) ----
        bf16_t* tmpB = ws + SD;
        bf16_t* Qp   = ws + 2 * SD;
        bf16_t* Kp   = ws + 3 * SD;
        bf16_t* Vt   = ws + 4 * SD;
        bf16_t* Wqb  = ws + 5 * SD;
        bf16_t* Wkb  = Wqb + WW;
        bf16_t* Wvb  = Wqb + 2 * WW;
        bf16_t* Wob  = Wqb + 3 * WW;

        cast4_f32_bf16<<<dim3(1024, 4), blk, 0, stream>>>(Wq, Wk, Wv, Wo, Wqb, Wkb, Wvb, Wob, 262144);
        qkv_gemm<<<dim3(1536), blk, 0, stream>>>(q, k, v, Wqb, Wkb, Wvb, Qp, Kp, Vt, cs);
        attn_fused<<<dim3(2048), blk, 0, stream>>>(Qp, Kp, Vt, vl, tmpB);
        gemm_out<<<dim3(512), blk, 0, stream>>>(tmpB, Wob, out);
    }
}

// Round 8
// 317.765 us; speedup vs baseline: 1.0067x; 1.0067x over previous
//
#include <hip/hip_runtime.h>
#include <hip/hip_bf16.h>

using bf16_t = __bf16;
using bf16x8 = __attribute__((ext_vector_type(8))) __bf16;
using bf16x4 = __attribute__((ext_vector_type(4))) __bf16;
using f32x4  = __attribute__((ext_vector_type(4))) float;

#define S_  2048
#define D_  1024

typedef __attribute__((address_space(1))) unsigned int glb_u32;
typedef __attribute__((address_space(3))) unsigned int lds_u32;

__device__ __forceinline__ void async_cp16(const void* g, void* lds) {
    __builtin_amdgcn_global_load_lds(
        (glb_u32*)(unsigned long long)g,
        (lds_u32*)(unsigned int)(unsigned long long)lds,
        16, 0, 0);
}

// ---------------- all f32 -> bf16 casts in one dispatch ----------------
// y=0..2: activations q,k,v (2M float4); y=3..6: weights (256K float4).
__global__ __launch_bounds__(256) void cast7(const float* __restrict__ q, const float* __restrict__ k,
                                             const float* __restrict__ v, const float* __restrict__ Wq,
                                             const float* __restrict__ Wk, const float* __restrict__ Wv,
                                             const float* __restrict__ Wo,
                                             bf16_t* __restrict__ oq, bf16_t* __restrict__ ok,
                                             bf16_t* __restrict__ ov, bf16_t* __restrict__ oWq,
                                             bf16_t* __restrict__ oWk, bf16_t* __restrict__ oWv,
                                             bf16_t* __restrict__ oWo) {
    int y = blockIdx.y;
    int i = blockIdx.x * 256 + threadIdx.x;
    const float* s; bf16_t* d; int n4;
    if      (y == 0) { s = q;  d = oq;  n4 = 2097152; }
    else if (y == 1) { s = k;  d = ok;  n4 = 2097152; }
    else if (y == 2) { s = v;  d = ov;  n4 = 2097152; }
    else if (y == 3) { s = Wq; d = oWq; n4 = 262144;  }
    else if (y == 4) { s = Wk; d = oWk; n4 = 262144;  }
    else if (y == 5) { s = Wv; d = oWv; n4 = 262144;  }
    else             { s = Wo; d = oWo; n4 = 262144;  }
    if (i >= n4) return;
    float4 f = reinterpret_cast<const float4*>(s)[i];
    bf16x4 o;
    o[0] = (bf16_t)f.x; o[1] = (bf16_t)f.y; o[2] = (bf16_t)f.z; o[3] = (bf16_t)f.w;
    reinterpret_cast<bf16x4*>(d)[i] = o;
}

// ---------------- weights f32 -> bf16 (fallback path) ----------------
__global__ __launch_bounds__(256) void cast4_f32_bf16(const float* __restrict__ a, const float* __restrict__ b,
                                                      const float* __restrict__ c, const float* __restrict__ dd,
                                                      bf16_t* __restrict__ oa, bf16_t* __restrict__ ob,
                                                      bf16_t* __restrict__ oc, bf16_t* __restrict__ od, int n4) {
    int i = blockIdx.x * 256 + threadIdx.x;
    if (i >= n4) return;
    const float* s; bf16_t* d;
    int w = blockIdx.y;
    if      (w == 0) { s = a;  d = oa; }
    else if (w == 1) { s = b;  d = ob; }
    else if (w == 2) { s = c;  d = oc; }
    else             { s = dd; d = od; }
    float4 f = reinterpret_cast<const float4*>(s)[i];
    bf16x4 o;
    o[0] = (bf16_t)f.x; o[1] = (bf16_t)f.y; o[2] = (bf16_t)f.z; o[3] = (bf16_t)f.w;
    reinterpret_cast<bf16x4*>(d)[i] = o;
}

// ============ 8-phase-schedule GEMM, tile 128x256 (grid-balanced) ============
// C[M x 1024] = A[M x 1024] * W[1024 x 1024]^T, A/W bf16.
// BK=64, 16 K-tiles; 512 threads = 8 waves (2M x 4N), per-wave out 64x64.
// LDS 96KB: As[2][2][128x32] + Bs[2][2][256x32], pure global_load_lds staging
// (source-swizzled slot^((row>>1)&3), LDS DMA-linear). 1 WG/CU.
// 2 phases per K-tile (kh0,kh1); per phase:
//   8x ds_read_b128 -> stage 3 cp16 (A 1 + B 2, next tile same kh) ->
//   s_barrier -> lgkmcnt(0) -> sched_barrier(0) -> setprio(1) -> 16 MFMA ->
//   setprio(0) -> vmcnt(3) -> s_barrier
// Invariant: after each phase's vmcnt(3), exactly the newest 3 loads (one
// half-tile) are outstanding; the half-tile the NEXT phase reads has landed.
// Never drains to 0 mid-loop; last tile phase0 uses vmcnt(0).
// Grid balance (the round-7 fix): qkv 64m x 4n x 3z = 768 WGs = 3.0 exact
// rounds at 1 WG/CU (was 384 = 1.5, 25% waste); out 256 WGs = 1.0 round
// (was 128 = half the GPU idle).
// MODE 0: fused QKV (z0 scale=cs; z2 writes per-head V^T, s pre-permuted to
//         MFMA A-frag order: pos = q*8 + hi*4 + r). MODE 1: out-proj, C f32.
template <int MODE>
__global__ __launch_bounds__(512, 2) void gemm8(const bf16_t* __restrict__ Aq,
                                                const bf16_t* __restrict__ Ak,
                                                const bf16_t* __restrict__ Av,
                                                const bf16_t* __restrict__ Wq,
                                                const bf16_t* __restrict__ Wk,
                                                const bf16_t* __restrict__ Wv,
                                                bf16_t* __restrict__ Qp,
                                                bf16_t* __restrict__ Kp,
                                                bf16_t* __restrict__ Vt,
                                                float cs,
                                                float* __restrict__ Co) {
    __shared__ bf16_t As[2][2][128 * 32];   // [buf][khalf][row*32 + k]  8KB/half
    __shared__ bf16_t Bs[2][2][256 * 32];   // 16KB/half
    const int K = 1024;
    constexpr int NKT = 16;                 // K / 64
    int tid  = threadIdx.x;
    int lane = tid & 63, w = tid >> 6;
    int l15  = lane & 15, quad = lane >> 4;
    int wr = w >> 2, wc = w & 3;            // 2M x 4N wave grid, wave-tile 64x64

    int bid = blockIdx.x;
    int xcd = bid & 7, r = bid >> 3;
    int z = 0, r2 = r;
    if (MODE == 0) { z = r >> 5; r2 = r & 31; }
    int m0 = (xcd * 8 + (r2 & 7)) * 128;    // 64 m-blocks, 8 per XCD
    int n0 = (r2 >> 3) * 256;               // 4 n-blocks

    const bf16_t *Ag, *Bg;
    if (MODE == 0) {
        Ag = (z == 0) ? Aq : (z == 1) ? Ak : Av;
        Bg = (z == 0) ? Wq : (z == 1) ? Wk : Wv;
    } else { Ag = Aq; Bg = Wq; }

    // staging addresses (source swizzle baked in; LDS dst linear for DMA)
    // A half-tile 128x32 = 8KB = 1 cp16/thread; B half-tile 256x32 = 2 cp16.
    const bf16_t* aS; const bf16_t* bS[2]; int bOff[2];
    {
        int row = tid >> 2, s = tid & 3;
        aS = Ag + (size_t)(m0 + row) * K + ((s ^ ((row >> 1) & 3)) * 8);
    }
#pragma unroll
    for (int j = 0; j < 2; j++) {
        int c = j * 512 + tid;
        int row = c >> 2, s = c & 3;
        bS[j] = Bg + (size_t)(n0 + row) * K + ((s ^ ((row >> 1) & 3)) * 8);
        bOff[j] = c * 8;
    }
    auto stage = [&](int buf, int t, int kh) {     // 3 loads: A, B0, B1
        int koff = t * 64 + kh * 32;
        async_cp16(aS + koff,    &As[buf][kh][tid * 8]);
        async_cp16(bS[0] + koff, &Bs[buf][kh][bOff[0]]);
        async_cp16(bS[1] + koff, &Bs[buf][kh][bOff[1]]);
    };

    // fragment read offsets (swizzled, 2-way = free)
    int aoff[4], boff[4];
#pragma unroll
    for (int i = 0; i < 4; i++) {
        int row = wr * 64 + i * 16 + l15;
        aoff[i] = row * 32 + ((quad ^ ((row >> 1) & 3)) * 8);
    }
#pragma unroll
    for (int jn = 0; jn < 4; jn++) {
        int row = wc * 64 + jn * 16 + l15;
        boff[jn] = row * 32 + ((quad ^ ((row >> 1) & 3)) * 8);
    }

    f32x4 acc[4][4] = {};

    // prologue: both halves of tile 0; land kh0, keep kh1 in flight
    stage(0, 0, 0);
    stage(0, 0, 1);
    asm volatile("s_waitcnt vmcnt(3)" ::: "memory");
    __builtin_amdgcn_s_barrier();

    for (int t = 0; t < NKT; ++t) {
        int buf = t & 1, nbuf = buf ^ 1;
        bool st = (t + 1 < NKT);
        bf16x8 af[4], bfr[4];

#pragma unroll
        for (int kh = 0; kh < 2; kh++) {
            const bf16_t* Ah = As[buf][kh];
            const bf16_t* Bh = Bs[buf][kh];
#pragma unroll
            for (int i = 0; i < 4; i++)  af[i]  = *reinterpret_cast<const bf16x8*>(&Ah[aoff[i]]);
#pragma unroll
            for (int jn = 0; jn < 4; jn++) bfr[jn] = *reinterpret_cast<const bf16x8*>(&Bh[boff[jn]]);
            if (st) stage(nbuf, t + 1, kh);
            __builtin_amdgcn_s_barrier();
            asm volatile("s_waitcnt lgkmcnt(0)" ::: "memory");
            __builtin_amdgcn_sched_barrier(0);
            __builtin_amdgcn_s_setprio(1);
#pragma unroll
            for (int i = 0; i < 4; i++)
#pragma unroll
                for (int jn = 0; jn < 4; jn++)
                    acc[i][jn] = __builtin_amdgcn_mfma_f32_16x16x32_bf16(af[i], bfr[jn], acc[i][jn], 0, 0, 0);
            __builtin_amdgcn_s_setprio(0);
            if (t == NKT - 1) asm volatile("s_waitcnt vmcnt(0)" ::: "memory");
            else              asm volatile("s_waitcnt vmcnt(3)" ::: "memory");
            __builtin_amdgcn_s_barrier();
        }
    }

    // ---- epilogue ----
    if (MODE == 0 && z == 2) {
#pragma unroll
        for (int i = 0; i < 4; i++)
#pragma unroll
            for (int jn = 0; jn < 4; jn++) {
                int m = m0 + wr * 64 + i * 16 + quad * 4;    // s-dim base (4 consecutive)
                int n = n0 + wc * 64 + jn * 16 + l15;        // d-dim
                bf16x4 o4;
#pragma unroll
                for (int rr = 0; rr < 4; rr++) o4[rr] = (bf16_t)acc[i][jn][rr];
                size_t vrow = (size_t)((m >> 11) * 16 + (n >> 6)) * 64 + (n & 63);
                int ml = m & 2047;
                int mp = (ml & ~31) | (((ml >> 2) & 3) << 3) | (((ml >> 4) & 1) << 2);
                *reinterpret_cast<bf16x4*>(&Vt[vrow * S_ + mp]) = o4;
            }
    } else if (MODE == 0) {
        bf16_t* CoH = (z == 0) ? Qp : Kp;
        float scale = (z == 0) ? cs : 1.0f;
#pragma unroll
        for (int i = 0; i < 4; i++)
#pragma unroll
            for (int jn = 0; jn < 4; jn++)
#pragma unroll
                for (int rr = 0; rr < 4; rr++) {
                    int m = m0 + wr * 64 + i * 16 + quad * 4 + rr;
                    int n = n0 + wc * 64 + jn * 16 + l15;
                    CoH[(size_t)m * 1024 + n] = (bf16_t)(acc[i][jn][rr] * scale);
                }
    } else {
#pragma unroll
        for (int i = 0; i < 4; i++)
#pragma unroll
            for (int jn = 0; jn < 4; jn++)
#pragma unroll
                for (int rr = 0; rr < 4; rr++) {
                    int m = m0 + wr * 64 + i * 16 + quad * 4 + rr;
                    int n = n0 + wc * 64 + jn * 16 + l15;
                    Co[(size_t)m * 1024 + n] = acc[i][jn][rr];
                }
    }
}

// ============== fallback path kernels (R6, used if ws too small) ==============
__global__ __launch_bounds__(256, 4) void qkv_gemm(const float* __restrict__ qf,
                                                   const float* __restrict__ kf,
                                                   const float* __restrict__ vf,
                                                   const bf16_t* __restrict__ Wqb,
                                                   const bf16_t* __restrict__ Wkb,
                                                   const bf16_t* __restrict__ Wvb,
                                                   bf16_t* __restrict__ Qp,
                                                   bf16_t* __restrict__ Kp,
                                                   bf16_t* __restrict__ Vt,
                                                   float cs) {
    __shared__ bf16_t As[2][128 * 32];
    __shared__ bf16_t Bs[3][128 * 32];
    const int K = 1024;
    int tid  = threadIdx.x;
    int lane = tid & 63;
    int w    = tid >> 6;
    int l15  = lane & 15, quad = lane >> 4;

    int bid = blockIdx.x;
    int xcd = bid & 7, idx = bid >> 3;
    int z   = idx >> 6;
    int rem = idx & 63;
    int m0 = (xcd * 8 + (rem & 7)) * 128;
    int n0 = (rem >> 3) * 128;
    int wm = (w >> 1) * 64, wn = (w & 1) * 64;

    const float*  Af; const bf16_t* Bt;
    if      (z == 0) { Af = qf; Bt = Wqb; }
    else if (z == 1) { Af = kf; Bt = Wkb; }
    else             { Af = vf; Bt = Wvb; }
    float scale = (z == 0) ? cs : 1.0f;

    const float* Ag = Af + (size_t)(m0 + (tid >> 2)) * K + (tid & 3) * 8;
    int arow = tid >> 2, aslot = tid & 3;
    int aoff = arow * 32 + ((aslot ^ ((arow >> 1) & 3)) * 8);

    const bf16_t* bSrc[2]; int bOff[2];
#pragma unroll
    for (int j = 0; j < 2; j++) {
        int linear = j * 256 + tid;
        int row = linear >> 2, s = linear & 3;
        bSrc[j] = Bt + (size_t)(n0 + row) * K + ((s ^ ((row >> 1) & 3)) * 8);
        bOff[j] = linear * 8;
    }

    float4 aE[4], aO[4];
    auto loadA = [&](float4* a, int k0) {
        const float* p = Ag + k0;
        a[0] = *reinterpret_cast<const float4*>(p);
        a[1] = *reinterpret_cast<const float4*>(p + 4);
        a[2] = *reinterpret_cast<const float4*>(p + (size_t)64 * K);
        a[3] = *reinterpret_cast<const float4*>(p + (size_t)64 * K + 4);
    };
    auto storeA = [&](bf16_t* dst, const float4* a) {
        bf16x8 o0, o1;
        o0[0] = (bf16_t)a[0].x; o0[1] = (bf16_t)a[0].y; o0[2] = (bf16_t)a[0].z; o0[3] = (bf16_t)a[0].w;
        o0[4] = (bf16_t)a[1].x; o0[5] = (bf16_t)a[1].y; o0[6] = (bf16_t)a[1].z; o0[7] = (bf16_t)a[1].w;
        o1[0] = (bf16_t)a[2].x; o1[1] = (bf16_t)a[2].y; o1[2] = (bf16_t)a[2].z; o1[3] = (bf16_t)a[2].w;
        o1[4] = (bf16_t)a[3].x; o1[5] = (bf16_t)a[3].y; o1[6] = (bf16_t)a[3].z; o1[7] = (bf16_t)a[3].w;
        *reinterpret_cast<bf16x8*>(dst + aoff)        = o0;
        *reinterpret_cast<bf16x8*>(dst + aoff + 2048) = o1;
    };
    auto stageB = [&](bf16_t* dst, int k0) {
        async_cp16(bSrc[0] + k0, dst + bOff[0]);
        async_cp16(bSrc[1] + k0, dst + bOff[1]);
    };

    f32x4 acc[4][4] = {};
    bf16_t *bRead = Bs[0], *bMid = Bs[1], *bStage = Bs[2];

    loadA(aE, 0);
    stageB(Bs[0], 0);
    loadA(aO, 32);
    stageB(Bs[1], 32);
    storeA(As[0], aE);
    asm volatile("s_waitcnt vmcnt(6) lgkmcnt(0)" ::: "memory");
    __builtin_amdgcn_s_barrier();

#pragma unroll 2
    for (int i = 0; i < 32; ++i) {
        int k2 = (i + 2 < 32) ? (i + 2) * 32 : 992;
        float4* aNew = (i & 1) ? aO : aE;
        loadA(aNew, k2);
        stageB(bStage, k2);

        const bf16_t* Ac = As[i & 1];
        bf16x8 af[4], bfr[4];
#pragma unroll
        for (int t = 0; t < 4; t++) {
            int ra = wm + t * 16 + l15;
            int rb = wn + t * 16 + l15;
            af[t]  = *reinterpret_cast<const bf16x8*>(&Ac[ra * 32 + ((quad ^ ((ra >> 1) & 3)) * 8)]);
            bfr[t] = *reinterpret_cast<const bf16x8*>(&bRead[rb * 32 + ((quad ^ ((rb >> 1) & 3)) * 8)]);
        }
#pragma unroll
        for (int mt = 0; mt < 4; mt++)
#pragma unroll
            for (int nt = 0; nt < 4; nt++)
                acc[mt][nt] = __builtin_amdgcn_mfma_f32_16x16x32_bf16(af[mt], bfr[nt], acc[mt][nt], 0, 0, 0);

        if (i + 1 < 32) storeA(As[(i + 1) & 1], (i & 1) ? aE : aO);

        bf16_t* t0 = bRead; bRead = bMid; bMid = bStage; bStage = t0;
        asm volatile("s_waitcnt vmcnt(6) lgkmcnt(0)" ::: "memory");
        __builtin_amdgcn_s_barrier();
    }

    if (z == 2) {
#pragma unroll
        for (int mt = 0; mt < 4; mt++)
#pragma unroll
            for (int nt = 0; nt < 4; nt++) {
                int m = m0 + wm + mt * 16 + quad * 4;
                int n = n0 + wn + nt * 16 + l15;
                bf16x4 o4;
#pragma unroll
                for (int r = 0; r < 4; r++) o4[r] = (bf16_t)acc[mt][nt][r];
                size_t vrow = (size_t)((m >> 11) * 16 + (n >> 6)) * 64 + (n & 63);
                int ml = m & 2047;
                int mp = (ml & ~31) | (((ml >> 2) & 3) << 3) | (((ml >> 4) & 1) << 2);
                *reinterpret_cast<bf16x4*>(&Vt[vrow * S_ + mp]) = o4;
            }
    } else {
        bf16_t* Co = (z == 0) ? Qp : Kp;
#pragma unroll
        for (int mt = 0; mt < 4; mt++)
#pragma unroll
            for (int nt = 0; nt < 4; nt++)
#pragma unroll
                for (int r = 0; r < 4; r++) {
                    int m = m0 + wm + mt * 16 + quad * 4 + r;
                    int n = n0 + wn + nt * 16 + l15;
                    Co[(size_t)m * 1024 + n] = (bf16_t)(acc[mt][nt][r] * scale);
                }
    }
}

// ---------------- fused masked attention (measured-best 81us version) ----------------
__global__ __launch_bounds__(256) void attn_fused(const bf16_t* __restrict__ Qp,
                                                  const bf16_t* __restrict__ Kp,
                                                  const bf16_t* __restrict__ Vt,
                                                  const int* __restrict__ vlen_p,
                                                  bf16_t* __restrict__ Out) {
    __shared__ bf16_t smem[4][64 * 64];

    int tid  = threadIdx.x;
    int lane = tid & 63, w = tid >> 6;
    int l15  = lane & 15, quad = lane >> 4;

    int nk[4], ord[4] = {0, 1, 2, 3};
#pragma unroll
    for (int i = 0; i < 4; i++) nk[i] = (vlen_p[i] + 63) >> 6;
#pragma unroll
    for (int i = 0; i < 3; i++)
#pragma unroll
        for (int j = 0; j < 3 - i; j++)
            if (nk[ord[j + 1]] > nk[ord[j]]) { int t = ord[j]; ord[j] = ord[j + 1]; ord[j + 1] = t; }

    int bid  = blockIdx.x;
    int b    = ord[bid >> 9];
    int t    = bid & 511;
    int h    = (t & 7) * 2 + ((t >> 3) & 1);
    int qblk = t >> 4;
    int vlen = vlen_p[b];
    int nkb  = (vlen + 63) >> 6;

    const bf16_t* Qg = Qp + (size_t)(b * S_ + qblk * 64) * D_ + h * 64;
    const bf16_t* Kg = Kp + (size_t)b * S_ * D_ + h * 64;
    const bf16_t* Vg = Vt + (size_t)(b * 16 + h) * 64 * S_;

    int r0 = tid >> 3, s0 = tid & 7;
    int sx = (s0 ^ (r0 & 7)) * 8;
    const bf16_t* kS0 = Kg + (size_t)r0 * D_ + sx;
    const bf16_t* kS1 = kS0 + (size_t)32 * D_;
    const bf16_t* vS0 = Vg + (size_t)r0 * S_ + sx;
    const bf16_t* vS1 = vS0 + (size_t)32 * S_;

    {
        const bf16_t* qS0 = Qg + (size_t)r0 * D_ + sx;
        async_cp16(qS0,                   smem[2] + tid * 8);
        async_cp16(qS0 + (size_t)32 * D_, smem[2] + tid * 8 + 2048);
        async_cp16(kS0, smem[0] + tid * 8);
        async_cp16(kS1, smem[0] + tid * 8 + 2048);
        async_cp16(vS0, smem[1] + tid * 8);
        async_cp16(vS1, smem[1] + tid * 8 + 2048);
    }
    __syncthreads();

    bf16x8 qf[2];
    {
        int row = w * 16 + l15, x = row & 7;
#pragma unroll
        for (int kk = 0; kk < 2; kk++)
            qf[kk] = *reinterpret_cast<const bf16x8*>(&smem[2][row * 64 + ((kk * 4 + quad) ^ x) * 8]);
    }
    __syncthreads();

    f32x4 o[4] = {};
    float l_st = 0.f;

    for (int kb = 0; kb < nkb; kb++) {
        int cur = kb & 1;
        if (kb + 1 < nkb) {
            int nxt = cur ^ 1;
            kS0 += (size_t)64 * D_; kS1 += (size_t)64 * D_;
            vS0 += 64;              vS1 += 64;
            async_cp16(kS0, smem[nxt * 2]     + tid * 8);
            async_cp16(kS1, smem[nxt * 2]     + tid * 8 + 2048);
            async_cp16(vS0, smem[nxt * 2 + 1] + tid * 8);
            async_cp16(vS1, smem[nxt * 2 + 1] + tid * 8 + 2048);
        }
        const bf16_t* Kc = smem[cur * 2];
        const bf16_t* Vc = smem[cur * 2 + 1];

        f32x4 sc[4] = {};
#pragma unroll
        for (int nt = 0; nt < 4; nt++) {
            int row = nt * 16 + l15, x = row & 7;
#pragma unroll
            for (int kk = 0; kk < 2; kk++) {
                bf16x8 kf = *reinterpret_cast<const bf16x8*>(&Kc[row * 64 + ((kk * 4 + quad) ^ x) * 8]);
                sc[nt] = __builtin_amdgcn_mfma_f32_16x16x32_bf16(kf, qf[kk], sc[nt], 0, 0, 0);
            }
        }

        bool partial = (vlen & 63) && (kb == nkb - 1);
        bf16x8 pf[2];
        float lacc = 0.f;
        if (!partial) {
#pragma unroll
            for (int nt = 0; nt < 4; nt++)
#pragma unroll
                for (int r = 0; r < 4; r++) {
                    float p = __builtin_exp2f(sc[nt][r]);
                    lacc += p;
                    pf[nt >> 1][(nt & 1) * 4 + r] = (bf16_t)p;
                }
        } else {
#pragma unroll
            for (int nt = 0; nt < 4; nt++)
#pragma unroll
                for (int r = 0; r < 4; r++) {
                    float p = __builtin_exp2f(sc[nt][r]);
                    if (kb * 64 + nt * 16 + quad * 4 + r >= vlen) p = 0.f;
                    lacc += p;
                    pf[nt >> 1][(nt & 1) * 4 + r] = (bf16_t)p;
                }
        }
        l_st += lacc;

#pragma unroll
        for (int np = 0; np < 2; np++)
#pragma unroll
            for (int dt = 0; dt < 4; dt++) {
                int row = dt * 16 + l15, x = row & 7;
                bf16x8 vfr = *reinterpret_cast<const bf16x8*>(&Vc[row * 64 + ((np * 4 + quad) ^ x) * 8]);
                o[dt] = __builtin_amdgcn_mfma_f32_16x16x32_bf16(vfr, pf[np], o[dt], 0, 0, 0);
            }

        __syncthreads();
    }

    float l = l_st;
    l += __shfl_xor(l, 16);
    l += __shfl_xor(l, 32);
    float inv = 1.0f / l;

    bf16_t* T = smem[0];
    {
        int row = w * 16 + l15, x = row & 7;
#pragma unroll
        for (int dt = 0; dt < 4; dt++) {
            bf16x4 o4;
#pragma unroll
            for (int r = 0; r < 4; r++) o4[r] = (bf16_t)(o[dt][r] * inv);
            int slot = dt * 2 + (quad >> 1);
            *reinterpret_cast<bf16x4*>(&T[row * 64 + (slot ^ x) * 8 + (quad & 1) * 4]) = o4;
        }
    }
    __syncthreads();
    {
        int row = tid >> 2, ch = tid & 3, x = row & 7;
        size_t obase = (size_t)(b * S_ + qblk * 64 + row) * D_ + h * 64 + ch * 16;
        bf16x8 f0 = *reinterpret_cast<const bf16x8*>(&T[row * 64 + ((ch * 2)     ^ x) * 8]);
        bf16x8 f1 = *reinterpret_cast<const bf16x8*>(&T[row * 64 + ((ch * 2 + 1) ^ x) * 8]);
        *reinterpret_cast<bf16x8*>(&Out[obase])     = f0;
        *reinterpret_cast<bf16x8*>(&Out[obase + 8]) = f1;
    }
}

// ---------------- fallback output GEMM (R6 ring) ----------------
__global__ __launch_bounds__(256) void gemm_out(const bf16_t* __restrict__ A,
                                                const bf16_t* __restrict__ Bt,
                                                float* __restrict__ C) {
    __shared__ bf16_t As[3][128 * 32];
    __shared__ bf16_t Bs[3][128 * 32];
    const int K = 1024;
    int tid  = threadIdx.x;
    int lane = tid & 63;
    int w    = tid >> 6;
    int l15  = lane & 15, quad = lane >> 4;

    int bid = blockIdx.x;
    int xcd = bid & 7, idx = bid >> 3;
    int m0 = (xcd * 8 + (idx & 7)) * 128;
    int n0 = (idx >> 3) * 128;
    int wm = (w >> 1) * 64, wn = (w & 1) * 64;

    const bf16_t* aSrc[2]; const bf16_t* bSrc[2];
    int dOff[2];
#pragma unroll
    for (int j = 0; j < 2; j++) {
        int linear = j * 256 + tid;
        int row = linear >> 2, s = linear & 3;
        int sw = (s ^ ((row >> 1) & 3)) * 8;
        aSrc[j] = A  + (size_t)(m0 + row) * K + sw;
        bSrc[j] = Bt + (size_t)(n0 + row) * K + sw;
        dOff[j] = linear * 8;
    }

    auto stage = [&](int buf, int koff) {
#pragma unroll
        for (int j = 0; j < 2; j++) async_cp16(aSrc[j] + koff, &As[buf][dOff[j]]);
#pragma unroll
        for (int j = 0; j < 2; j++) async_cp16(bSrc[j] + koff, &Bs[buf][dOff[j]]);
    };

    f32x4 acc[4][4] = {};

    stage(0, 0);
    stage(1, 32);

    int cur = 0, nx2 = 2;
    for (int i = 0; i < 32; ++i) {
        if (i == 31) asm volatile("s_waitcnt vmcnt(0)" ::: "memory");
        else         asm volatile("s_waitcnt vmcnt(4)" ::: "memory");
        __builtin_amdgcn_s_barrier();
        if (i + 2 < 32) stage(nx2, (i + 2) * 32);

        bf16x8 af[4], bfr[4];
#pragma unroll
        for (int t = 0; t < 4; t++) {
            int ra = wm + t * 16 + l15;
            int rb = wn + t * 16 + l15;
            af[t]  = *reinterpret_cast<const bf16x8*>(&As[cur][ra * 32 + ((quad ^ ((ra >> 1) & 3)) * 8)]);
            bfr[t] = *reinterpret_cast<const bf16x8*>(&Bs[cur][rb * 32 + ((quad ^ ((rb >> 1) & 3)) * 8)]);
        }
#pragma unroll
        for (int mt = 0; mt < 4; mt++)
#pragma unroll
            for (int nt = 0; nt < 4; nt++)
                acc[mt][nt] = __builtin_amdgcn_mfma_f32_16x16x32_bf16(af[mt], bfr[nt], acc[mt][nt], 0, 0, 0);

        cur = (cur == 2) ? 0 : cur + 1;
        nx2 = (nx2 == 2) ? 0 : nx2 + 1;
    }

#pragma unroll
    for (int mt = 0; mt < 4; mt++)
#pragma unroll
        for (int nt = 0; nt < 4; nt++)
#pragma unroll
            for (int r = 0; r < 4; r++) {
                int m = m0 + wm + mt * 16 + quad * 4 + r;
                int n = n0 + wn + nt * 16 + l15;
                C[(size_t)m * 1024 + n] = acc[mt][nt][r];
            }
}

extern "C" void kernel_launch(void* const* d_in, const int* in_sizes, int n_in,
                              void* d_out, int out_size, void* d_ws, size_t ws_size,
                              hipStream_t stream) {
    const float* q  = (const float*)d_in[0];
    const float* k  = (const float*)d_in[1];
    const float* v  = (const float*)d_in[2];
    const int*   vl = (const int*)d_in[3];
    const float* Wq = (const float*)d_in[4];
    const float* Wk = (const float*)d_in[5];
    const float* Wv = (const float*)d_in[6];
    const float* Wo = (const float*)d_in[7];
    float* out = (float*)d_out;

    bf16_t* ws = (bf16_t*)d_ws;
    const size_t SD = (size_t)8192 * 1024;
    const size_t WW = (size_t)1024 * 1024;
    const float cs = 0.18033688f;  // (1/8)*log2(e) baked into Q projection
    dim3 blk(256);

    size_t need = (6 * SD + 4 * WW) * sizeof(bf16_t);   // ~109 MB
    if (ws_size >= need) {
        // ---- 8-phase path: one cast dispatch, grid-balanced gemm8 ----
        bf16_t* qb  = ws;              // q bf16; reused as attn output after qkv
        bf16_t* kb  = ws + SD;
        bf16_t* vb  = ws + 2 * SD;
        bf16_t* Qp  = ws + 3 * SD;
        bf16_t* Kp  = ws + 4 * SD;
        bf16_t* Vt  = ws + 5 * SD;
        bf16_t* Wqb = ws + 6 * SD;
        bf16_t* Wkb = Wqb + WW;
        bf16_t* Wvb = Wqb + 2 * WW;
        bf16_t* Wob = Wqb + 3 * WW;

        cast7<<<dim3(8192, 7), blk, 0, stream>>>(q, k, v, Wq, Wk, Wv, Wo,
                                                 qb, kb, vb, Wqb, Wkb, Wvb, Wob);
        gemm8<0><<<dim3(768), dim3(512), 0, stream>>>(qb, kb, vb, Wqb, Wkb, Wvb, Qp, Kp, Vt, cs, nullptr);
        attn_fused<<<dim3(2048), blk, 0, stream>>>(Qp, Kp, Vt, vl, qb);
        gemm8<1><<<dim3(256), dim3(512), 0, stream>>>(qb, nullptr, nullptr, Wob, nullptr, nullptr,
                                                      nullptr, nullptr, nullptr, 1.0f, out);
    } else {
        // ---- fallback: R6 path (92.3 MB footprint, known-good) ----
        bf16_t* tmpB = ws + SD;
        bf16_t* Qp   = ws + 2 * SD;
        bf16_t* Kp   = ws + 3 * SD;
        bf16_t* Vt   = ws + 4 * SD;
        bf16_t* Wqb  = ws + 5 * SD;
        bf16_t* Wkb  = Wqb + WW;
        bf16_t* Wvb  = Wqb + 2 * WW;
        bf16_t* Wob  = Wqb + 3 * WW;

        cast4_f32_bf16<<<dim3(1024, 4), blk, 0, stream>>>(Wq, Wk, Wv, Wo, Wqb, Wkb, Wvb, Wob, 262144);
        qkv_gemm<<<dim3(1536), blk, 0, stream>>>(q, k, v, Wqb, Wkb, Wvb, Qp, Kp, Vt, cs);
        attn_fused<<<dim3(2048), blk, 0, stream>>>(Qp, Kp, Vt, vl, tmpB);
        gemm_out<<<dim3(512), blk, 0, stream>>>(tmpB, Wob, out);
    }
}

// Round 10
// 307.222 us; speedup vs baseline: 1.0412x; 1.0343x over previous
//
#include <hip/hip_runtime.h>
#include <hip/hip_bf16.h>

using bf16_t = __bf16;
using bf16x8 = __attribute__((ext_vector_type(8))) __bf16;
using bf16x4 = __attribute__((ext_vector_type(4))) __bf16;
using f32x4  = __attribute__((ext_vector_type(4))) float;

#define S_  2048
#define D_  1024

typedef __attribute__((address_space(1))) unsigned int glb_u32;
typedef __attribute__((address_space(3))) unsigned int lds_u32;

__device__ __forceinline__ void async_cp16(const void* g, void* lds) {
    __builtin_amdgcn_global_load_lds(
        (glb_u32*)(unsigned long long)g,
        (lds_u32*)(unsigned int)(unsigned long long)lds,
        16, 0, 0);
}

// ---------------- all f32 -> bf16 casts in one dispatch ----------------
__global__ __launch_bounds__(256) void cast7(const float* __restrict__ q, const float* __restrict__ k,
                                             const float* __restrict__ v, const float* __restrict__ Wq,
                                             const float* __restrict__ Wk, const float* __restrict__ Wv,
                                             const float* __restrict__ Wo,
                                             bf16_t* __restrict__ oq, bf16_t* __restrict__ ok,
                                             bf16_t* __restrict__ ov, bf16_t* __restrict__ oWq,
                                             bf16_t* __restrict__ oWk, bf16_t* __restrict__ oWv,
                                             bf16_t* __restrict__ oWo) {
    int y = blockIdx.y;
    int i = blockIdx.x * 256 + threadIdx.x;
    const float* s; bf16_t* d; int n4;
    if      (y == 0) { s = q;  d = oq;  n4 = 2097152; }
    else if (y == 1) { s = k;  d = ok;  n4 = 2097152; }
    else if (y == 2) { s = v;  d = ov;  n4 = 2097152; }
    else if (y == 3) { s = Wq; d = oWq; n4 = 262144;  }
    else if (y == 4) { s = Wk; d = oWk; n4 = 262144;  }
    else if (y == 5) { s = Wv; d = oWv; n4 = 262144;  }
    else             { s = Wo; d = oWo; n4 = 262144;  }
    if (i >= n4) return;
    float4 f = reinterpret_cast<const float4*>(s)[i];
    bf16x4 o;
    o[0] = (bf16_t)f.x; o[1] = (bf16_t)f.y; o[2] = (bf16_t)f.z; o[3] = (bf16_t)f.w;
    reinterpret_cast<bf16x4*>(d)[i] = o;
}

// ---------------- weights f32 -> bf16 (fallback path) ----------------
__global__ __launch_bounds__(256) void cast4_f32_bf16(const float* __restrict__ a, const float* __restrict__ b,
                                                      const float* __restrict__ c, const float* __restrict__ dd,
                                                      bf16_t* __restrict__ oa, bf16_t* __restrict__ ob,
                                                      bf16_t* __restrict__ oc, bf16_t* __restrict__ od, int n4) {
    int i = blockIdx.x * 256 + threadIdx.x;
    if (i >= n4) return;
    const float* s; bf16_t* d;
    int w = blockIdx.y;
    if      (w == 0) { s = a;  d = oa; }
    else if (w == 1) { s = b;  d = ob; }
    else if (w == 2) { s = c;  d = oc; }
    else             { s = dd; d = od; }
    float4 f = reinterpret_cast<const float4*>(s)[i];
    bf16x4 o;
    o[0] = (bf16_t)f.x; o[1] = (bf16_t)f.y; o[2] = (bf16_t)f.z; o[3] = (bf16_t)f.w;
    reinterpret_cast<bf16x4*>(d)[i] = o;
}

// ========== 8-phase-schedule GEMM, tile 128x256, ring-5 @ BK=32 ==========
// BK=32, 32 K-tiles; 512 threads = 8 waves (2M x 4N), per-wave out 64x64.
// LDS 120KB (<=128KB proven on this stack, unlike R9's 144KB):
// As[5][128x32] (8KB/buf) + Bs[5][256x32] (16KB/buf) -- 5-buffer ring staging
// FOUR K-tiles ahead. Tile tau issued at iter tau-4, needed at end of iter
// tau-1 -> ~3 iters (~900 cy) of cover ~= HBM latency (R8's depth-1 gave ~450).
// Wait math: during iter t, outstanding after staging = tiles {t+1..t+4} = 12
// loads; end-of-iter s_waitcnt vmcnt(9) completes exactly tile t+1. Uniform
// everywhere (prologue: stage 0..3, vmcnt(9) lands tile 0). Tail: clamped
// dummy stages into consumed buffers keep counts uniform (checked t=28..31).
// Per iter: 8x ds_read_b128 -> stage 3 cp16 -> s_barrier -> lgkmcnt(0) ->
// sched_barrier(0) -> setprio(1) -> 16 MFMA -> setprio(0) -> vmcnt(9) -> s_barrier.
// Grid balance: qkv 64m x 4n x 3z = 768 WGs = 3.0 rounds; out 256 = 1.0 round.
// MODE 0: fused QKV (z0 scale=cs; z2 writes per-head V^T, s pre-permuted to
//         MFMA A-frag order: pos = q*8 + hi*4 + r). MODE 1: out-proj, C f32.
template <int MODE>
__global__ __launch_bounds__(512, 2) void gemm8(const bf16_t* __restrict__ Aq,
                                                const bf16_t* __restrict__ Ak,
                                                const bf16_t* __restrict__ Av,
                                                const bf16_t* __restrict__ Wq,
                                                const bf16_t* __restrict__ Wk,
                                                const bf16_t* __restrict__ Wv,
                                                bf16_t* __restrict__ Qp,
                                                bf16_t* __restrict__ Kp,
                                                bf16_t* __restrict__ Vt,
                                                float cs,
                                                float* __restrict__ Co) {
    __shared__ bf16_t As[5][128 * 32];   // 8KB per buffer
    __shared__ bf16_t Bs[5][256 * 32];   // 16KB per buffer
    const int K = 1024;
    constexpr int NKT = 32;              // K / 32
    int tid  = threadIdx.x;
    int lane = tid & 63, w = tid >> 6;
    int l15  = lane & 15, quad = lane >> 4;
    int wr = w >> 2, wc = w & 3;         // 2M x 4N wave grid, wave-tile 64x64

    int bid = blockIdx.x;
    int xcd = bid & 7, r = bid >> 3;
    int z = 0, r2 = r;
    if (MODE == 0) { z = r >> 5; r2 = r & 31; }
    int m0 = (xcd * 8 + (r2 & 7)) * 128; // 64 m-blocks, 8 per XCD
    int n0 = (r2 >> 3) * 256;            // 4 n-blocks

    const bf16_t *Ag, *Bg;
    if (MODE == 0) {
        Ag = (z == 0) ? Aq : (z == 1) ? Ak : Av;
        Bg = (z == 0) ? Wq : (z == 1) ? Wk : Wv;
    } else { Ag = Aq; Bg = Wq; }

    // staging addresses (source swizzle baked in; LDS dst linear for DMA)
    // A tile 128x32 = 512 chunks = 1 cp16/thread; B tile 256x32 = 2 cp16/thread.
    const bf16_t* aS; const bf16_t* bS[2]; int bOff[2];
    {
        int row = tid >> 2, s = tid & 3;
        aS = Ag + (size_t)(m0 + row) * K + ((s ^ ((row >> 1) & 3)) * 8);
    }
#pragma unroll
    for (int j = 0; j < 2; j++) {
        int c = j * 512 + tid;
        int row = c >> 2, s = c & 3;
        bS[j] = Bg + (size_t)(n0 + row) * K + ((s ^ ((row >> 1) & 3)) * 8);
        bOff[j] = c * 8;
    }
    auto stage = [&](int buf, int t) {   // 3 loads: A, B0, B1
        int koff = t * 32;
        async_cp16(aS + koff,    &As[buf][tid * 8]);
        async_cp16(bS[0] + koff, &Bs[buf][bOff[0]]);
        async_cp16(bS[1] + koff, &Bs[buf][bOff[1]]);
    };

    // fragment read offsets (swizzled, 2-way = free)
    int aoff[4], boff[4];
#pragma unroll
    for (int i = 0; i < 4; i++) {
        int row = wr * 64 + i * 16 + l15;
        aoff[i] = row * 32 + ((quad ^ ((row >> 1) & 3)) * 8);
    }
#pragma unroll
    for (int jn = 0; jn < 4; jn++) {
        int row = wc * 64 + jn * 16 + l15;
        boff[jn] = row * 32 + ((quad ^ ((row >> 1) & 3)) * 8);
    }

    f32x4 acc[4][4] = {};

    // prologue: tiles 0..3 staged (12 loads); land tile 0, keep 9 in flight
    stage(0, 0); stage(1, 1); stage(2, 2); stage(3, 3);
    asm volatile("s_waitcnt vmcnt(9)" ::: "memory");
    __builtin_amdgcn_s_barrier();

    int cur = 0, st4 = 4;
    for (int t = 0; t < NKT; ++t) {
        int tn = (t + 4 < NKT) ? t + 4 : NKT - 1;   // clamped dummy keeps counts uniform
        const bf16_t* Ah = As[cur];
        const bf16_t* Bh = Bs[cur];
        bf16x8 af[4], bfr[4];
#pragma unroll
        for (int i = 0; i < 4; i++)  af[i]  = *reinterpret_cast<const bf16x8*>(&Ah[aoff[i]]);
#pragma unroll
        for (int jn = 0; jn < 4; jn++) bfr[jn] = *reinterpret_cast<const bf16x8*>(&Bh[boff[jn]]);
        stage(st4, tn);
        __builtin_amdgcn_s_barrier();
        asm volatile("s_waitcnt lgkmcnt(0)" ::: "memory");
        __builtin_amdgcn_sched_barrier(0);
        __builtin_amdgcn_s_setprio(1);
#pragma unroll
        for (int i = 0; i < 4; i++)
#pragma unroll
            for (int jn = 0; jn < 4; jn++)
                acc[i][jn] = __builtin_amdgcn_mfma_f32_16x16x32_bf16(af[i], bfr[jn], acc[i][jn], 0, 0, 0);
        __builtin_amdgcn_s_setprio(0);
        asm volatile("s_waitcnt vmcnt(9)" ::: "memory");
        __builtin_amdgcn_s_barrier();
        cur = (cur == 4) ? 0 : cur + 1;
        st4 = (st4 == 4) ? 0 : st4 + 1;
    }

    // ---- epilogue ----
    if (MODE == 0 && z == 2) {
#pragma unroll
        for (int i = 0; i < 4; i++)
#pragma unroll
            for (int jn = 0; jn < 4; jn++) {
                int m = m0 + wr * 64 + i * 16 + quad * 4;    // s-dim base (4 consecutive)
                int n = n0 + wc * 64 + jn * 16 + l15;        // d-dim
                bf16x4 o4;
#pragma unroll
                for (int rr = 0; rr < 4; rr++) o4[rr] = (bf16_t)acc[i][jn][rr];
                size_t vrow = (size_t)((m >> 11) * 16 + (n >> 6)) * 64 + (n & 63);
                int ml = m & 2047;
                int mp = (ml & ~31) | (((ml >> 2) & 3) << 3) | (((ml >> 4) & 1) << 2);
                *reinterpret_cast<bf16x4*>(&Vt[vrow * S_ + mp]) = o4;
            }
    } else if (MODE == 0) {
        bf16_t* CoH = (z == 0) ? Qp : Kp;
        float scale = (z == 0) ? cs : 1.0f;
#pragma unroll
        for (int i = 0; i < 4; i++)
#pragma unroll
            for (int jn = 0; jn < 4; jn++)
#pragma unroll
                for (int rr = 0; rr < 4; rr++) {
                    int m = m0 + wr * 64 + i * 16 + quad * 4 + rr;
                    int n = n0 + wc * 64 + jn * 16 + l15;
                    CoH[(size_t)m * 1024 + n] = (bf16_t)(acc[i][jn][rr] * scale);
                }
    } else {
#pragma unroll
        for (int i = 0; i < 4; i++)
#pragma unroll
            for (int jn = 0; jn < 4; jn++)
#pragma unroll
                for (int rr = 0; rr < 4; rr++) {
                    int m = m0 + wr * 64 + i * 16 + quad * 4 + rr;
                    int n = n0 + wc * 64 + jn * 16 + l15;
                    Co[(size_t)m * 1024 + n] = acc[i][jn][rr];
                }
    }
}

// ============== fallback path kernels (R6, used if ws too small) ==============
__global__ __launch_bounds__(256, 4) void qkv_gemm(const float* __restrict__ qf,
                                                   const float* __restrict__ kf,
                                                   const float* __restrict__ vf,
                                                   const bf16_t* __restrict__ Wqb,
                                                   const bf16_t* __restrict__ Wkb,
                                                   const bf16_t* __restrict__ Wvb,
                                                   bf16_t* __restrict__ Qp,
                                                   bf16_t* __restrict__ Kp,
                                                   bf16_t* __restrict__ Vt,
                                                   float cs) {
    __shared__ bf16_t As[2][128 * 32];
    __shared__ bf16_t Bs[3][128 * 32];
    const int K = 1024;
    int tid  = threadIdx.x;
    int lane = tid & 63;
    int w    = tid >> 6;
    int l15  = lane & 15, quad = lane >> 4;

    int bid = blockIdx.x;
    int xcd = bid & 7, idx = bid >> 3;
    int z   = idx >> 6;
    int rem = idx & 63;
    int m0 = (xcd * 8 + (rem & 7)) * 128;
    int n0 = (rem >> 3) * 128;
    int wm = (w >> 1) * 64, wn = (w & 1) * 64;

    const float*  Af; const bf16_t* Bt;
    if      (z == 0) { Af = qf; Bt = Wqb; }
    else if (z == 1) { Af = kf; Bt = Wkb; }
    else             { Af = vf; Bt = Wvb; }
    float scale = (z == 0) ? cs : 1.0f;

    const float* Ag = Af + (size_t)(m0 + (tid >> 2)) * K + (tid & 3) * 8;
    int arow = tid >> 2, aslot = tid & 3;
    int aoff = arow * 32 + ((aslot ^ ((arow >> 1) & 3)) * 8);

    const bf16_t* bSrc[2]; int bOff[2];
#pragma unroll
    for (int j = 0; j < 2; j++) {
        int linear = j * 256 + tid;
        int row = linear >> 2, s = linear & 3;
        bSrc[j] = Bt + (size_t)(n0 + row) * K + ((s ^ ((row >> 1) & 3)) * 8);
        bOff[j] = linear * 8;
    }

    float4 aE[4], aO[4];
    auto loadA = [&](float4* a, int k0) {
        const float* p = Ag + k0;
        a[0] = *reinterpret_cast<const float4*>(p);
        a[1] = *reinterpret_cast<const float4*>(p + 4);
        a[2] = *reinterpret_cast<const float4*>(p + (size_t)64 * K);
        a[3] = *reinterpret_cast<const float4*>(p + (size_t)64 * K + 4);
    };
    auto storeA = [&](bf16_t* dst, const float4* a) {
        bf16x8 o0, o1;
        o0[0] = (bf16_t)a[0].x; o0[1] = (bf16_t)a[0].y; o0[2] = (bf16_t)a[0].z; o0[3] = (bf16_t)a[0].w;
        o0[4] = (bf16_t)a[1].x; o0[5] = (bf16_t)a[1].y; o0[6] = (bf16_t)a[1].z; o0[7] = (bf16_t)a[1].w;
        o1[0] = (bf16_t)a[2].x; o1[1] = (bf16_t)a[2].y; o1[2] = (bf16_t)a[2].z; o1[3] = (bf16_t)a[2].w;
        o1[4] = (bf16_t)a[3].x; o1[5] = (bf16_t)a[3].y; o1[6] = (bf16_t)a[3].z; o1[7] = (bf16_t)a[3].w;
        *reinterpret_cast<bf16x8*>(dst + aoff)        = o0;
        *reinterpret_cast<bf16x8*>(dst + aoff + 2048) = o1;
    };
    auto stageB = [&](bf16_t* dst, int k0) {
        async_cp16(bSrc[0] + k0, dst + bOff[0]);
        async_cp16(bSrc[1] + k0, dst + bOff[1]);
    };

    f32x4 acc[4][4] = {};
    bf16_t *bRead = Bs[0], *bMid = Bs[1], *bStage = Bs[2];

    loadA(aE, 0);
    stageB(Bs[0], 0);
    loadA(aO, 32);
    stageB(Bs[1], 32);
    storeA(As[0], aE);
    asm volatile("s_waitcnt vmcnt(6) lgkmcnt(0)" ::: "memory");
    __builtin_amdgcn_s_barrier();

#pragma unroll 2
    for (int i = 0; i < 32; ++i) {
        int k2 = (i + 2 < 32) ? (i + 2) * 32 : 992;
        float4* aNew = (i & 1) ? aO : aE;
        loadA(aNew, k2);
        stageB(bStage, k2);

        const bf16_t* Ac = As[i & 1];
        bf16x8 af[4], bfr[4];
#pragma unroll
        for (int t = 0; t < 4; t++) {
            int ra = wm + t * 16 + l15;
            int rb = wn + t * 16 + l15;
            af[t]  = *reinterpret_cast<const bf16x8*>(&Ac[ra * 32 + ((quad ^ ((ra >> 1) & 3)) * 8)]);
            bfr[t] = *reinterpret_cast<const bf16x8*>(&bRead[rb * 32 + ((quad ^ ((rb >> 1) & 3)) * 8)]);
        }
#pragma unroll
        for (int mt = 0; mt < 4; mt++)
#pragma unroll
            for (int nt = 0; nt < 4; nt++)
                acc[mt][nt] = __builtin_amdgcn_mfma_f32_16x16x32_bf16(af[mt], bfr[nt], acc[mt][nt], 0, 0, 0);

        if (i + 1 < 32) storeA(As[(i + 1) & 1], (i & 1) ? aE : aO);

        bf16_t* t0 = bRead; bRead = bMid; bMid = bStage; bStage = t0;
        asm volatile("s_waitcnt vmcnt(6) lgkmcnt(0)" ::: "memory");
        __builtin_amdgcn_s_barrier();
    }

    if (z == 2) {
#pragma unroll
        for (int mt = 0; mt < 4; mt++)
#pragma unroll
            for (int nt = 0; nt < 4; nt++) {
                int m = m0 + wm + mt * 16 + quad * 4;
                int n = n0 + wn + nt * 16 + l15;
                bf16x4 o4;
#pragma unroll
                for (int r = 0; r < 4; r++) o4[r] = (bf16_t)acc[mt][nt][r];
                size_t vrow = (size_t)((m >> 11) * 16 + (n >> 6)) * 64 + (n & 63);
                int ml = m & 2047;
                int mp = (ml & ~31) | (((ml >> 2) & 3) << 3) | (((ml >> 4) & 1) << 2);
                *reinterpret_cast<bf16x4*>(&Vt[vrow * S_ + mp]) = o4;
            }
    } else {
        bf16_t* Co = (z == 0) ? Qp : Kp;
#pragma unroll
        for (int mt = 0; mt < 4; mt++)
#pragma unroll
            for (int nt = 0; nt < 4; nt++)
#pragma unroll
                for (int r = 0; r < 4; r++) {
                    int m = m0 + wm + mt * 16 + quad * 4 + r;
                    int n = n0 + wn + nt * 16 + l15;
                    Co[(size_t)m * 1024 + n] = (bf16_t)(acc[mt][nt][r] * scale);
                }
    }
}

// ---------------- fused masked attention ----------------
// l accumulated on the MFMA pipe via a ones-fragment (l = P . 1): 2 extra
// MFMA/iter on the cold pipe (21%) replace 16 v_add_f32/iter on the hot pipe
// (66%) and the epilogue cross-lane shuffles. ol's C-layout (col=l15=q)
// matches the PV accumulator, so ol[0] is this lane's l. Masked tiles stay
// correct: pf is zeroed before the MFMA.
__global__ __launch_bounds__(256) void attn_fused(const bf16_t* __restrict__ Qp,
                                                  const bf16_t* __restrict__ Kp,
                                                  const bf16_t* __restrict__ Vt,
                                                  const int* __restrict__ vlen_p,
                                                  bf16_t* __restrict__ Out) {
    __shared__ bf16_t smem[4][64 * 64];

    int tid  = threadIdx.x;
    int lane = tid & 63, w = tid >> 6;
    int l15  = lane & 15, quad = lane >> 4;

    int nk[4], ord[4] = {0, 1, 2, 3};
#pragma unroll
    for (int i = 0; i < 4; i++) nk[i] = (vlen_p[i] + 63) >> 6;
#pragma unroll
    for (int i = 0; i < 3; i++)
#pragma unroll
        for (int j = 0; j < 3 - i; j++)
            if (nk[ord[j + 1]] > nk[ord[j]]) { int t = ord[j]; ord[j] = ord[j + 1]; ord[j + 1] = t; }

    int bid  = blockIdx.x;
    int b    = ord[bid >> 9];
    int t    = bid & 511;
    int h    = (t & 7) * 2 + ((t >> 3) & 1);
    int qblk = t >> 4;
    int vlen = vlen_p[b];
    int nkb  = (vlen + 63) >> 6;

    const bf16_t* Qg = Qp + (size_t)(b * S_ + qblk * 64) * D_ + h * 64;
    const bf16_t* Kg = Kp + (size_t)b * S_ * D_ + h * 64;
    const bf16_t* Vg = Vt + (size_t)(b * 16 + h) * 64 * S_;

    int r0 = tid >> 3, s0 = tid & 7;
    int sx = (s0 ^ (r0 & 7)) * 8;
    const bf16_t* kS0 = Kg + (size_t)r0 * D_ + sx;
    const bf16_t* kS1 = kS0 + (size_t)32 * D_;
    const bf16_t* vS0 = Vg + (size_t)r0 * S_ + sx;
    const bf16_t* vS1 = vS0 + (size_t)32 * S_;

    {
        const bf16_t* qS0 = Qg + (size_t)r0 * D_ + sx;
        async_cp16(qS0,                   smem[2] + tid * 8);
        async_cp16(qS0 + (size_t)32 * D_, smem[2] + tid * 8 + 2048);
        async_cp16(kS0, smem[0] + tid * 8);
        async_cp16(kS1, smem[0] + tid * 8 + 2048);
        async_cp16(vS0, smem[1] + tid * 8);
        async_cp16(vS1, smem[1] + tid * 8 + 2048);
    }
    __syncthreads();

    bf16x8 qf[2];
    {
        int row = w * 16 + l15, x = row & 7;
#pragma unroll
        for (int kk = 0; kk < 2; kk++)
            qf[kk] = *reinterpret_cast<const bf16x8*>(&smem[2][row * 64 + ((kk * 4 + quad) ^ x) * 8]);
    }
    __syncthreads();

    bf16x8 ones8;
#pragma unroll
    for (int j = 0; j < 8; j++) ones8[j] = (bf16_t)1.0f;

    f32x4 o[4] = {};
    f32x4 ol = {};

    for (int kb = 0; kb < nkb; kb++) {
        int cur = kb & 1;
        if (kb + 1 < nkb) {
            int nxt = cur ^ 1;
            kS0 += (size_t)64 * D_; kS1 += (size_t)64 * D_;
            vS0 += 64;              vS1 += 64;
            async_cp16(kS0, smem[nxt * 2]     + tid * 8);
            async_cp16(kS1, smem[nxt * 2]     + tid * 8 + 2048);
            async_cp16(vS0, smem[nxt * 2 + 1] + tid * 8);
            async_cp16(vS1, smem[nxt * 2 + 1] + tid * 8 + 2048);
        }
        const bf16_t* Kc = smem[cur * 2];
        const bf16_t* Vc = smem[cur * 2 + 1];

        f32x4 sc[4] = {};
#pragma unroll
        for (int nt = 0; nt < 4; nt++) {
            int row = nt * 16 + l15, x = row & 7;
#pragma unroll
            for (int kk = 0; kk < 2; kk++) {
                bf16x8 kf = *reinterpret_cast<const bf16x8*>(&Kc[row * 64 + ((kk * 4 + quad) ^ x) * 8]);
                sc[nt] = __builtin_amdgcn_mfma_f32_16x16x32_bf16(kf, qf[kk], sc[nt], 0, 0, 0);
            }
        }

        bool partial = (vlen & 63) && (kb == nkb - 1);
        bf16x8 pf[2];
        if (!partial) {
#pragma unroll
            for (int nt = 0; nt < 4; nt++)
#pragma unroll
                for (int r = 0; r < 4; r++) {
                    float p = __builtin_exp2f(sc[nt][r]);
                    pf[nt >> 1][(nt & 1) * 4 + r] = (bf16_t)p;
                }
        } else {
#pragma unroll
            for (int nt = 0; nt < 4; nt++)
#pragma unroll
                for (int r = 0; r < 4; r++) {
                    float p = __builtin_exp2f(sc[nt][r]);
                    if (kb * 64 + nt * 16 + quad * 4 + r >= vlen) p = 0.f;
                    pf[nt >> 1][(nt & 1) * 4 + r] = (bf16_t)p;
                }
        }

        // l = P . 1 on the MFMA pipe (replaces 16 VALU adds + final shuffle)
        ol = __builtin_amdgcn_mfma_f32_16x16x32_bf16(ones8, pf[0], ol, 0, 0, 0);
        ol = __builtin_amdgcn_mfma_f32_16x16x32_bf16(ones8, pf[1], ol, 0, 0, 0);

#pragma unroll
        for (int np = 0; np < 2; np++)
#pragma unroll
            for (int dt = 0; dt < 4; dt++) {
                int row = dt * 16 + l15, x = row & 7;
                bf16x8 vfr = *reinterpret_cast<const bf16x8*>(&Vc[row * 64 + ((np * 4 + quad) ^ x) * 8]);
                o[dt] = __builtin_amdgcn_mfma_f32_16x16x32_bf16(vfr, pf[np], o[dt], 0, 0, 0);
            }

        __syncthreads();
    }

    float inv = 1.0f / ol[0];

    bf16_t* T = smem[0];
    {
        int row = w * 16 + l15, x = row & 7;
#pragma unroll
        for (int dt = 0; dt < 4; dt++) {
            bf16x4 o4;
#pragma unroll
            for (int r = 0; r < 4; r++) o4[r] = (bf16_t)(o[dt][r] * inv);
            int slot = dt * 2 + (quad >> 1);
            *reinterpret_cast<bf16x4*>(&T[row * 64 + (slot ^ x) * 8 + (quad & 1) * 4]) = o4;
        }
    }
    __syncthreads();
    {
        int row = tid >> 2, ch = tid & 3, x = row & 7;
        size_t obase = (size_t)(b * S_ + qblk * 64 + row) * D_ + h * 64 + ch * 16;
        bf16x8 f0 = *reinterpret_cast<const bf16x8*>(&T[row * 64 + ((ch * 2)     ^ x) * 8]);
        bf16x8 f1 = *reinterpret_cast<const bf16x8*>(&T[row * 64 + ((ch * 2 + 1) ^ x) * 8]);
        *reinterpret_cast<bf16x8*>(&Out[obase])     = f0;
        *reinterpret_cast<bf16x8*>(&Out[obase + 8]) = f1;
    }
}

// ---------------- fallback output GEMM (R6 ring) ----------------
__global__ __launch_bounds__(256) void gemm_out(const bf16_t* __restrict__ A,
                                                const bf16_t* __restrict__ Bt,
                                                float* __restrict__ C) {
    __shared__ bf16_t As[3][128 * 32];
    __shared__ bf16_t Bs[3][128 * 32];
    const int K = 1024;
    int tid  = threadIdx.x;
    int lane = tid & 63;
    int w    = tid >> 6;
    int l15  = lane & 15, quad = lane >> 4;

    int bid = blockIdx.x;
    int xcd = bid & 7, idx = bid >> 3;
    int m0 = (xcd * 8 + (idx & 7)) * 128;
    int n0 = (idx >> 3) * 128;
    int wm = (w >> 1) * 64, wn = (w & 1) * 64;

    const bf16_t* aSrc[2]; const bf16_t* bSrc[2];
    int dOff[2];
#pragma unroll
    for (int j = 0; j < 2; j++) {
        int linear = j * 256 + tid;
        int row = linear >> 2, s = linear & 3;
        int sw = (s ^ ((row >> 1) & 3)) * 8;
        aSrc[j] = A  + (size_t)(m0 + row) * K + sw;
        bSrc[j] = Bt + (size_t)(n0 + row) * K + sw;
        dOff[j] = linear * 8;
    }

    auto stage = [&](int buf, int koff) {
#pragma unroll
        for (int j = 0; j < 2; j++) async_cp16(aSrc[j] + koff, &As[buf][dOff[j]]);
#pragma unroll
        for (int j = 0; j < 2; j++) async_cp16(bSrc[j] + koff, &Bs[buf][dOff[j]]);
    };

    f32x4 acc[4][4] = {};

    stage(0, 0);
    stage(1, 32);

    int cur = 0, nx2 = 2;
    for (int i = 0; i < 32; ++i) {
        if (i == 31) asm volatile("s_waitcnt vmcnt(0)" ::: "memory");
        else         asm volatile("s_waitcnt vmcnt(4)" ::: "memory");
        __builtin_amdgcn_s_barrier();
        if (i + 2 < 32) stage(nx2, (i + 2) * 32);

        bf16x8 af[4], bfr[4];
#pragma unroll
        for (int t = 0; t < 4; t++) {
            int ra = wm + t * 16 + l15;
            int rb = wn + t * 16 + l15;
            af[t]  = *reinterpret_cast<const bf16x8*>(&As[cur][ra * 32 + ((quad ^ ((ra >> 1) & 3)) * 8)]);
            bfr[t] = *reinterpret_cast<const bf16x8*>(&Bs[cur][rb * 32 + ((quad ^ ((rb >> 1) & 3)) * 8)]);
        }
#pragma unroll
        for (int mt = 0; mt < 4; mt++)
#pragma unroll
            for (int nt = 0; nt < 4; nt++)
                acc[mt][nt] = __builtin_amdgcn_mfma_f32_16x16x32_bf16(af[mt], bfr[nt], acc[mt][nt], 0, 0, 0);

        cur = (cur == 2) ? 0 : cur + 1;
        nx2 = (nx2 == 2) ? 0 : nx2 + 1;
    }

#pragma unroll
    for (int mt = 0; mt < 4; mt++)
#pragma unroll
        for (int nt = 0; nt < 4; nt++)
#pragma unroll
            for (int r = 0; r < 4; r++) {
                int m = m0 + wm + mt * 16 + quad * 4 + r;
                int n = n0 + wn + nt * 16 + l15;
                C[(size_t)m * 1024 + n] = acc[mt][nt][r];
            }
}

extern "C" void kernel_launch(void* const* d_in, const int* in_sizes, int n_in,
                              void* d_out, int out_size, void* d_ws, size_t ws_size,
                              hipStream_t stream) {
    const float* q  = (const float*)d_in[0];
    const float* k  = (const float*)d_in[1];
    const float* v  = (const float*)d_in[2];
    const int*   vl = (const int*)d_in[3];
    const float* Wq = (const float*)d_in[4];
    const float* Wk = (const float*)d_in[5];
    const float* Wv = (const float*)d_in[6];
    const float* Wo = (const float*)d_in[7];
    float* out = (float*)d_out;

    bf16_t* ws = (bf16_t*)d_ws;
    const size_t SD = (size_t)8192 * 1024;
    const size_t WW = (size_t)1024 * 1024;
    const float cs = 0.18033688f;  // (1/8)*log2(e) baked into Q projection
    dim3 blk(256);

    size_t need = (6 * SD + 4 * WW) * sizeof(bf16_t);   // ~109 MB
    if (ws_size >= need) {
        // ---- 8-phase path: one cast dispatch, ring-5 gemm8 ----
        bf16_t* qb  = ws;              // q bf16; reused as attn output after qkv
        bf16_t* kb  = ws + SD;
        bf16_t* vb  = ws + 2 * SD;
        bf16_t* Qp  = ws + 3 * SD;
        bf16_t* Kp  = ws + 4 * SD;
        bf16_t* Vt  = ws + 5 * SD;
        bf16_t* Wqb = ws + 6 * SD;
        bf16_t* Wkb = Wqb + WW;
        bf16_t* Wvb = Wqb + 2 * WW;
        bf16_t* Wob = Wqb + 3 * WW;

        cast7<<<dim3(8192, 7), blk, 0, stream>>>(q, k, v, Wq, Wk, Wv, Wo,
                                                 qb, kb, vb, Wqb, Wkb, Wvb, Wob);
        gemm8<0><<<dim3(768), dim3(512), 0, stream>>>(qb, kb, vb, Wqb, Wkb, Wvb, Qp, Kp, Vt, cs, nullptr);
        attn_fused<<<dim3(2048), blk, 0, stream>>>(Qp, Kp, Vt, vl, qb);
        gemm8<1><<<dim3(256), dim3(512), 0, stream>>>(qb, nullptr, nullptr, Wob, nullptr, nullptr,
                                                      nullptr, nullptr, nullptr, 1.0f, out);
    } else {
        // ---- fallback: R6 path (92.3 MB footprint, known-good) ----
        bf16_t* tmpB = ws + SD;
        bf16_t* Qp   = ws + 2 * SD;
        bf16_t* Kp   = ws + 3 * SD;
        bf16_t* Vt   = ws + 4 * SD;
        bf16_t* Wqb  = ws + 5 * SD;
        bf16_t* Wkb  = Wqb + WW;
        bf16_t* Wvb  = Wqb + 2 * WW;
        bf16_t* Wob  = Wqb + 3 * WW;

        cast4_f32_bf16<<<dim3(1024, 4), blk, 0, stream>>>(Wq, Wk, Wv, Wo, Wqb, Wkb, Wvb, Wob, 262144);
        qkv_gemm<<<dim3(1536), blk, 0, stream>>>(q, k, v, Wqb, Wkb, Wvb, Qp, Kp, Vt, cs);
        attn_fused<<<dim3(2048), blk, 0, stream>>>(Qp, Kp, Vt, vl, tmpB);
        gemm_out<<<dim3(512), blk, 0, stream>>>(tmpB, Wob, out);
    }
}